// Round 1
// baseline (1499.082 us; speedup 1.0000x reference)
//
#include <hip/hip_runtime.h>
#include <math.h>

#define NB 16384
#define DD 1024

typedef unsigned short u16;

// ---------- helpers ----------
__device__ __forceinline__ float bf2f(u16 u){
  return __uint_as_float(((unsigned)u) << 16);
}
__device__ __forceinline__ u16 f2bf(float f){
  unsigned u = __float_as_uint(f);
  return (u16)((u + 0x7fffu + ((u >> 16) & 1u)) >> 16);   // RNE
}
__device__ __forceinline__ float wredsum(float x){
  #pragma unroll
  for(int o = 32; o >= 1; o >>= 1) x += __shfl_xor(x, o);
  return x;
}
__device__ __forceinline__ float wredmax(float x){
  #pragma unroll
  for(int o = 32; o >= 1; o >>= 1) x = fmaxf(x, __shfl_xor(x, o));
  return x;
}
__device__ __forceinline__ void load8(const float* p, float* o){
  float4 x0 = *(const float4*)p, x1 = *(const float4*)(p + 4);
  o[0]=x0.x;o[1]=x0.y;o[2]=x0.z;o[3]=x0.w;o[4]=x1.x;o[5]=x1.y;o[6]=x1.z;o[7]=x1.w;
}
__device__ __forceinline__ void load8(const u16* p, float* o){
  float4 raw = *(const float4*)p;           // 8 bf16 in 16B
  const u16* u = (const u16*)&raw;
  #pragma unroll
  for(int j = 0; j < 8; j++) o[j] = bf2f(u[j]);
}

// ---------- K1: per-row stats, w_uni, w_bi, unimodal ----------
// 1 wave per row, 4 waves per block.
__global__ __launch_bounds__(256) void k1_stats(
    const float* __restrict__ x, const float* __restrict__ attW,
    const float* __restrict__ attb, float* __restrict__ stats,
    u16* __restrict__ uni, float* __restrict__ tw)
{
  int wave = threadIdx.x >> 6, lane = threadIdx.x & 63;
  int r = blockIdx.x * 4 + wave;
  const float* xr = x + (size_t)r * 3 * DD;
  float a[16], v[16], l[16];
  float dA=0.f,dV=0.f,dL=0.f, mA=-1e30f,mV=-1e30f,mL=-1e30f;
  #pragma unroll
  for(int i = 0; i < 16; i++){
    int k = lane + i*64;
    a[i] = xr[k]; v[i] = xr[DD+k]; l[i] = xr[2*DD+k];
    float w = attW[k];
    dA = fmaf(a[i], w, dA); dV = fmaf(v[i], w, dV); dL = fmaf(l[i], w, dL);
    mA = fmaxf(mA, a[i]); mV = fmaxf(mV, v[i]); mL = fmaxf(mL, l[i]);
  }
  dA = wredsum(dA); dV = wredsum(dV); dL = wredsum(dL);
  mA = wredmax(mA); mV = wredmax(mV); mL = wredmax(mL);

  float Sa=0.f,Sv=0.f,Sl=0.f,Eav=0.f,Eal=0.f,Evl=0.f;
  #pragma unroll
  for(int i = 0; i < 16; i++){
    float ea = expf(a[i]-mA), ev = expf(v[i]-mV), el = expf(l[i]-mL);
    Sa += ea; Sv += ev; Sl += el;
    Eav += ea*ev; Eal += ea*el; Evl += ev*el;
  }
  Sa = wredsum(Sa); Sv = wredsum(Sv); Sl = wredsum(Sl);
  Eav = wredsum(Eav); Eal = wredsum(Eal); Evl = wredsum(Evl);

  float ab = attb[0];
  float ta = tanhf(dA + ab), tv = tanhf(dV + ab), tl = tanhf(dL + ab);
  float mm = fmaxf(ta, fmaxf(tv, tl));
  float e0 = expf(ta-mm), e1 = expf(tv-mm), e2 = expf(tl-mm);
  float ss = e0 + e1 + e2;
  float sa = e0/ss, sv = e1/ss, sl = e2/ss;
  float dav = Eav/(Sa*Sv), dal = Eal/(Sa*Sl), dvl = Evl/(Sv*Sl);
  float sav = (sa+sv)/(dav+0.5f);
  float sal = (sa+sl)/(dal+0.5f);
  float svl = (sv+sl)/(dvl+0.5f);
  float m2 = fmaxf(sav, fmaxf(sal, svl));
  float f0 = expf(sav-m2), f1 = expf(sal-m2), f2 = expf(svl-m2);
  float s2 = f0 + f1 + f2;
  float wb0 = f0/s2, wb1 = f1/s2, wb2 = f2/s2;

  if(lane == 0){
    float* st = stats + (size_t)r*24;
    st[0]=sa; st[1]=sv; st[2]=sl;
    st[3]=wb0; st[4]=wb1; st[5]=wb2;
    st[6]=sav; st[7]=sal; st[8]=svl;
    st[9]=mA; st[10]=Sa; st[11]=mV; st[12]=Sv; st[13]=mL; st[14]=Sl;
    float* twr = tw + (size_t)r*12;
    twr[0]=sa; twr[1]=sv; twr[2]=sl; twr[3]=wb0; twr[4]=wb1; twr[5]=wb2;
  }
  #pragma unroll
  for(int i = 0; i < 16; i++){
    int k = lane + i*64;
    uni[(size_t)r*DD + k] = f2bf((sa*a[i] + sv*v[i] + sl*l[i]) * (1.0f/3.0f));
  }
}

// ---------- K2/K4: layer-1 GEMM  (M,1024) @ Wcat(1024,128) ----------
// Wcat[k][c] = c<64 ? W1[k][c] : W1[1024+k][c-64]  (U | V halves)
// 128x128 tile, 256 threads, 8x8 micro-tile, BK=16.
template<typename T>
__global__ __launch_bounds__(256) void k_gemm1(
    const T* __restrict__ src, const float* __restrict__ W1,
    float* __restrict__ UV)
{
  __shared__ __align__(16) float As[16][132];
  __shared__ __align__(16) float Bs[16][132];
  int tid = threadIdx.x;
  int mb = blockIdx.x * 128;
  int ty = tid >> 4, tx = tid & 15;
  int r0 = ty * 8, c0 = tx * 8;
  int arow = tid >> 1, akoff = (tid & 1) * 8;
  int brow = tid >> 4, bcoff = (tid & 15) * 8;

  float acc[8][8] = {};

  for(int k0 = 0; k0 < 1024; k0 += 16){
    float av8[8];
    load8(src + (size_t)(mb + arow)*1024 + k0 + akoff, av8);
    #pragma unroll
    for(int j = 0; j < 8; j++) As[akoff + j][arow] = av8[j];
    {
      const float* p = (bcoff < 64)
          ? (W1 + (size_t)(k0 + brow)*64 + bcoff)
          : (W1 + (size_t)(1024 + k0 + brow)*64 + (bcoff - 64));
      float4 b0 = *(const float4*)p;
      float4 b1v = *(const float4*)(p + 4);
      *(float4*)&Bs[brow][bcoff]     = b0;
      *(float4*)&Bs[brow][bcoff + 4] = b1v;
    }
    __syncthreads();
    #pragma unroll
    for(int kk = 0; kk < 16; kk++){
      float ar[8], br[8];
      *(float4*)ar       = *(const float4*)&As[kk][r0];
      *(float4*)(ar + 4) = *(const float4*)&As[kk][r0 + 4];
      *(float4*)br       = *(const float4*)&Bs[kk][c0];
      *(float4*)(br + 4) = *(const float4*)&Bs[kk][c0 + 4];
      #pragma unroll
      for(int i = 0; i < 8; i++)
        #pragma unroll
        for(int j = 0; j < 8; j++)
          acc[i][j] = fmaf(ar[i], br[j], acc[i][j]);
    }
    __syncthreads();
  }
  #pragma unroll
  for(int i = 0; i < 8; i++){
    float* o = UV + (size_t)(mb + r0 + i)*128 + c0;
    *(float4*)o       = make_float4(acc[i][0],acc[i][1],acc[i][2],acc[i][3]);
    *(float4*)(o + 4) = make_float4(acc[i][4],acc[i][5],acc[i][6],acc[i][7]);
  }
}

// ---------- K3: layer-2 bimodal -> a_v, a_l, v_l (bf16) ----------
// 8 rows x 256 cols per block; thread owns 1 row, 8 cols, all 3 pairs.
__global__ __launch_bounds__(256) void k3_bi2(
    const float* __restrict__ UV1, const float* __restrict__ W2,
    const float* __restrict__ b1, const float* __restrict__ b2,
    const float* __restrict__ stats, u16* __restrict__ avalvl)
{
  __shared__ __align__(16) float W2s[64][256];
  __shared__ float ts[8][3][64];
  int tid = threadIdx.x;
  int rb = blockIdx.x * 8;
  int cb = blockIdx.y * 256;

  #pragma unroll
  for(int t = 0; t < 16; t++){
    int f4 = tid + t*256;
    int kr = f4 >> 6, c4 = (f4 & 63) << 2;
    *(float4*)&W2s[kr][c4] = *(const float4*)&W2[(size_t)kr*DD + cb + c4];
  }
  #pragma unroll
  for(int t = 0; t < 6; t++){
    int f = tid + t*256;                 // 8*3*64 = 1536
    int rr = f / 192, rem = f % 192;
    int p = rem >> 6, j = rem & 63;
    int R = rb + rr;
    int up = (p == 2) ? 1 : 0;           // U source: a1,a1,v1
    int vp = (p == 0) ? 1 : 2;           // V source: v1,l1,l1
    float tv = UV1[(size_t)(3*R + up)*128 + j]
             + UV1[(size_t)(3*R + vp)*128 + 64 + j] + b1[j];
    ts[rr][p][j] = tv > 0.f ? tv : 0.2f*tv;
  }
  __syncthreads();

  int rr = tid >> 5;
  int c0 = (tid & 31) << 3;
  float acc[3][8] = {};
  #pragma unroll 4
  for(int kk = 0; kk < 64; kk++){
    float w8[8];
    *(float4*)w8       = *(const float4*)&W2s[kk][c0];
    *(float4*)(w8 + 4) = *(const float4*)&W2s[kk][c0 + 4];
    float t0 = ts[rr][0][kk], t1 = ts[rr][1][kk], t2 = ts[rr][2][kk];
    #pragma unroll
    for(int j = 0; j < 8; j++){
      acc[0][j] = fmaf(t0, w8[j], acc[0][j]);
      acc[1][j] = fmaf(t1, w8[j], acc[1][j]);
      acc[2][j] = fmaf(t2, w8[j], acc[2][j]);
    }
  }
  int R = rb + rr;
  const float* st = stats + (size_t)R*24;
  #pragma unroll
  for(int p = 0; p < 3; p++){
    float wbp = st[3 + p];
    __align__(16) u16 o8[8];
    #pragma unroll
    for(int j = 0; j < 8; j++){
      int c = cb + c0 + j;
      float g = tanhf(acc[p][j] + b2[c]);
      float val = wbp * g;
      o8[j] = f2bf(val > 0.f ? val : 0.01f*val);
    }
    *(float4*)&avalvl[(size_t)(3*R + p)*DD + cb + c0] = *(float4*)o8;
  }
}

// ---------- K3s: softmax stats of a_v/a_l/v_l + cross dots -> w_tri ----------
__global__ __launch_bounds__(256) void k3s_stats2(
    const u16* __restrict__ avalvl, const float* __restrict__ x,
    float* __restrict__ stats, float* __restrict__ tw)
{
  int wave = threadIdx.x >> 6, lane = threadIdx.x & 63;
  int r = blockIdx.x * 4 + wave;
  const u16*   pv = avalvl + (size_t)3*r*DD;
  const float* xr = x      + (size_t)3*r*DD;
  float av[16], al[16], vl[16], a1[16], v1[16], l1[16];
  float mav=-1e30f, mal=-1e30f, mvl=-1e30f;
  #pragma unroll
  for(int i = 0; i < 16; i++){
    int k = lane + i*64;
    av[i] = bf2f(pv[k]); al[i] = bf2f(pv[DD+k]); vl[i] = bf2f(pv[2*DD+k]);
    a1[i] = xr[k]; v1[i] = xr[DD+k]; l1[i] = xr[2*DD+k];
    mav = fmaxf(mav, av[i]); mal = fmaxf(mal, al[i]); mvl = fmaxf(mvl, vl[i]);
  }
  mav = wredmax(mav); mal = wredmax(mal); mvl = wredmax(mvl);

  float* st = stats + (size_t)r*24;
  float sa=st[0], sv=st[1], sl=st[2];
  float sav=st[6], sal=st[7], svl=st[8];
  float mA=st[9], Sa=st[10], mV=st[11], Sv=st[12], mL=st[13], Sl=st[14];

  float Savv=0.f,Sall=0.f,Svll=0.f,E1=0.f,E2=0.f,E3=0.f,E4=0.f,E5=0.f,E6=0.f;
  #pragma unroll
  for(int i = 0; i < 16; i++){
    float eav = expf(av[i]-mav), eal = expf(al[i]-mal), evl = expf(vl[i]-mvl);
    Savv += eav; Sall += eal; Svll += evl;
    float ea = expf(a1[i]-mA), ev = expf(v1[i]-mV), el = expf(l1[i]-mL);
    E1 += eav*evl; E2 += eav*eal; E3 += eal*evl;
    E4 += eav*el;  E5 += eal*ev;  E6 += evl*ea;
  }
  Savv = wredsum(Savv); Sall = wredsum(Sall); Svll = wredsum(Svll);
  E1 = wredsum(E1); E2 = wredsum(E2); E3 = wredsum(E3);
  E4 = wredsum(E4); E5 = wredsum(E5); E6 = wredsum(E6);

  float d1 = E1/(Savv*Svll), d2 = E2/(Savv*Sall), d3 = E3/(Sall*Svll);
  float d4 = E4/(Savv*Sl),   d5 = E5/(Sall*Sv),   d6 = E6/(Svll*Sa);
  float t0 = (sav+svl)/(d1+0.5f);   // savvl
  float t1 = (sav+sal)/(d2+0.5f);   // saavl
  float t2 = (sal+svl)/(d3+0.5f);   // savll
  float t3 = (sav+sl)/(d4+0.5f);    // savl
  float t4 = (sal+sv)/(d5+0.5f);    // salv
  float t5 = (sa+svl)/(d6+0.5f);    // svla
  float mx = fmaxf(fmaxf(fmaxf(t0,t1),fmaxf(t2,t3)),fmaxf(t4,t5));
  float g0=expf(t0-mx),g1=expf(t1-mx),g2=expf(t2-mx);
  float g3=expf(t3-mx),g4=expf(t4-mx),g5=expf(t5-mx);
  float gs = g0+g1+g2+g3+g4+g5;
  if(lane == 0){
    float wt[6] = {g0/gs,g1/gs,g2/gs,g3/gs,g4/gs,g5/gs};
    float* twr = tw + (size_t)r*12;
    #pragma unroll
    for(int p = 0; p < 6; p++){ st[15+p] = wt[p]; twr[6+p] = wt[p]; }
  }
}

// ---------- K5: layer-2 trimodal -> tri (bf16) ----------
__global__ __launch_bounds__(256) void k5_tri2(
    const float* __restrict__ UV2, const float* __restrict__ UV1,
    const float* __restrict__ W2, const float* __restrict__ b1,
    const float* __restrict__ b2, const float* __restrict__ stats,
    u16* __restrict__ tri)
{
  __shared__ __align__(16) float W2s[64][256];
  __shared__ float ts[8][6][64];
  int tid = threadIdx.x;
  int rb = blockIdx.x * 8;
  int cb = blockIdx.y * 256;

  #pragma unroll
  for(int t = 0; t < 16; t++){
    int f4 = tid + t*256;
    int kr = f4 >> 6, c4 = (f4 & 63) << 2;
    *(float4*)&W2s[kr][c4] = *(const float4*)&W2[(size_t)kr*DD + cb + c4];
  }
  #pragma unroll
  for(int t = 0; t < 12; t++){
    int f = tid + t*256;                  // 8*6*64 = 3072
    int rr = f / 384, rem = f % 384;
    int p = rem >> 6, j = rem & 63;
    int R = rb + rr;
    int up = (0x210200 >> (p*4)) & 15;    // 0,0,2,0,1,2  (a_v,a_v,v_l,a_v,a_l,v_l)
    int vp = (0x012112 >> (p*4)) & 15;    // 2,1,1,2,1,0  (v_l,a_l,a_l,l1,v1,a1)
    const float* VB = (p < 3) ? UV2 : UV1;
    float tv = UV2[(size_t)(3*R + up)*128 + j]
             + VB[(size_t)(3*R + vp)*128 + 64 + j] + b1[j];
    ts[rr][p][j] = tv > 0.f ? tv : 0.2f*tv;
  }
  __syncthreads();

  int rr = tid >> 5;
  int c0 = (tid & 31) << 3;
  float acc[6][8] = {};
  #pragma unroll 4
  for(int kk = 0; kk < 64; kk++){
    float w8[8];
    *(float4*)w8       = *(const float4*)&W2s[kk][c0];
    *(float4*)(w8 + 4) = *(const float4*)&W2s[kk][c0 + 4];
    float tv[6];
    #pragma unroll
    for(int p = 0; p < 6; p++) tv[p] = ts[rr][p][kk];
    #pragma unroll
    for(int p = 0; p < 6; p++)
      #pragma unroll
      for(int j = 0; j < 8; j++)
        acc[p][j] = fmaf(tv[p], w8[j], acc[p][j]);
  }
  int R = rb + rr;
  const float* st = stats + (size_t)R*24;
  float wt[6];
  #pragma unroll
  for(int p = 0; p < 6; p++) wt[p] = st[15+p];
  __align__(16) u16 o8[8];
  #pragma unroll
  for(int j = 0; j < 8; j++){
    int c = cb + c0 + j;
    float b2c = b2[c];
    float sum = 0.f;
    #pragma unroll
    for(int p = 0; p < 6; p++){
      float g = tanhf(acc[p][j] + b2c);
      float val = wt[p] * g;
      sum += val > 0.f ? val : 0.01f*val;
    }
    o8[j] = f2bf(sum * (1.0f/6.0f));
  }
  *(float4*)&tri[(size_t)R*DD + cb + c0] = *(float4*)o8;
}

// ---------- K6: BN + (B,3072)@(3072,50) + tanh + 50x50 + 50x8 + softmax ----------
__global__ __launch_bounds__(256) void k6_final(
    const u16* __restrict__ uni, const u16* __restrict__ avalvl,
    const u16* __restrict__ tri,
    const float* __restrict__ gamma, const float* __restrict__ beta,
    const float* __restrict__ l1W, const float* __restrict__ l1b,
    const float* __restrict__ l2W, const float* __restrict__ l2b,
    const float* __restrict__ l3W, const float* __restrict__ l3b,
    float* __restrict__ y2out)
{
  __shared__ float Fs[64][68];   // [row][kc]
  __shared__ __align__(16) float Ws[64][68];   // [kc][col]
  __shared__ float Ys[64][57];
  __shared__ float Ys2[64][57];
  int tid = threadIdx.x;
  int rb = blockIdx.x * 64;
  int ty = tid >> 4, tx = tid & 15;
  int r0 = ty * 4, c0 = tx * 4;
  const float gsc = 1.0f / sqrtf(1.0f + 1e-5f);

  float acc[4][4] = {};
  for(int k0 = 0; k0 < 3072; k0 += 64){
    int part = k0 >> 10;
    #pragma unroll
    for(int t = 0; t < 16; t++){
      int f = tid + t*256;
      int row = f >> 6, kc = f & 63;
      int k = k0 + kc, kk = k & 1023;
      int R = rb + row;
      float fv;
      if(part == 0)      fv = bf2f(uni[(size_t)R*DD + kk]);
      else if(part == 1) fv = (bf2f(avalvl[(size_t)(3*R)*DD + kk])
                             + bf2f(avalvl[(size_t)(3*R+1)*DD + kk])
                             + bf2f(avalvl[(size_t)(3*R+2)*DD + kk])) * (1.0f/3.0f);
      else               fv = bf2f(tri[(size_t)R*DD + kk]);
      Fs[row][kc] = fv * (gamma[k] * gsc) + beta[k];
    }
    #pragma unroll
    for(int t = 0; t < 16; t++){
      int f = tid + t*256;
      int kr = f >> 6, c = f & 63;
      Ws[kr][c] = (c < 50) ? l1W[(size_t)(k0 + kr)*50 + c] : 0.f;
    }
    __syncthreads();
    #pragma unroll 8
    for(int kk = 0; kk < 64; kk++){
      float a4[4], b4[4];
      #pragma unroll
      for(int i = 0; i < 4; i++) a4[i] = Fs[r0 + i][kk];
      *(float4*)b4 = *(const float4*)&Ws[kk][c0];
      #pragma unroll
      for(int i = 0; i < 4; i++)
        #pragma unroll
        for(int j = 0; j < 4; j++)
          acc[i][j] = fmaf(a4[i], b4[j], acc[i][j]);
    }
    __syncthreads();
  }
  #pragma unroll
  for(int i = 0; i < 4; i++)
    #pragma unroll
    for(int j = 0; j < 4; j++){
      int c = c0 + j;
      if(c < 50) Ys[r0 + i][c] = tanhf(acc[i][j] + l1b[c]);
    }
  __syncthreads();

  // y = tanh(Ys @ l2W + b)
  float acc2[4][4] = {};
  int cc[4];
  #pragma unroll
  for(int j = 0; j < 4; j++) cc[j] = (c0 + j < 50) ? (c0 + j) : 0;
  for(int kk = 0; kk < 50; kk++){
    float a4[4];
    #pragma unroll
    for(int i = 0; i < 4; i++) a4[i] = Ys[r0 + i][kk];
    #pragma unroll
    for(int j = 0; j < 4; j++){
      float w = l2W[kk*50 + cc[j]];
      #pragma unroll
      for(int i = 0; i < 4; i++) acc2[i][j] = fmaf(a4[i], w, acc2[i][j]);
    }
  }
  #pragma unroll
  for(int i = 0; i < 4; i++)
    #pragma unroll
    for(int j = 0; j < 4; j++){
      int c = c0 + j;
      if(c < 50) Ys2[r0 + i][c] = tanhf(acc2[i][j] + l2b[c]);
    }
  __syncthreads();

  // z = Ys2 @ l3W + b3 ; softmax over 8
  int row = tid >> 2, q = tid & 3;
  int ca = q*2, cb2 = q*2 + 1;
  float z0 = l3b[ca], z1 = l3b[cb2];
  for(int kk = 0; kk < 50; kk++){
    float yv = Ys2[row][kk];
    z0 = fmaf(yv, l3W[kk*8 + ca], z0);
    z1 = fmaf(yv, l3W[kk*8 + cb2], z1);
  }
  float m = fmaxf(z0, z1);
  m = fmaxf(m, __shfl_xor(m, 1));
  m = fmaxf(m, __shfl_xor(m, 2));
  float e0 = expf(z0 - m), e1 = expf(z1 - m);
  float s = e0 + e1;
  s += __shfl_xor(s, 1);
  s += __shfl_xor(s, 2);
  int R = rb + row;
  y2out[(size_t)R*8 + ca]  = e0 / s;
  y2out[(size_t)R*8 + cb2] = e1 / s;
}

// ---------- launch ----------
extern "C" void kernel_launch(void* const* d_in, const int* in_sizes, int n_in,
                              void* d_out, int out_size, void* d_ws, size_t ws_size,
                              hipStream_t stream)
{
  (void)in_sizes; (void)n_in; (void)out_size; (void)ws_size;
  const float* x    = (const float*)d_in[0];
  const float* attW = (const float*)d_in[1];
  const float* attb = (const float*)d_in[2];
  const float* gfW1 = (const float*)d_in[3];
  const float* gfb1 = (const float*)d_in[4];
  const float* gfW2 = (const float*)d_in[5];
  const float* gfb2 = (const float*)d_in[6];
  const float* bng  = (const float*)d_in[7];
  const float* bnb  = (const float*)d_in[8];
  const float* l1W  = (const float*)d_in[9];
  const float* l1b  = (const float*)d_in[10];
  const float* l2W  = (const float*)d_in[11];
  const float* l2b  = (const float*)d_in[12];
  const float* l3W  = (const float*)d_in[13];
  const float* l3b  = (const float*)d_in[14];

  float* out = (float*)d_out;
  float* tw  = out + (size_t)NB*8;

  // workspace layout (~220 MB)
  float* ws    = (float*)d_ws;
  float* stats = ws;                              // NB*24 f32
  float* UV1   = stats + (size_t)NB*24;           // 3*NB*128 f32
  float* UV2   = UV1 + (size_t)3*NB*128;          // 3*NB*128 f32
  u16* avalvl  = (u16*)(UV2 + (size_t)3*NB*128);  // 3*NB*DD bf16
  u16* uni     = avalvl + (size_t)3*NB*DD;        // NB*DD bf16
  u16* tri     = uni + (size_t)NB*DD;             // NB*DD bf16

  k1_stats<<<dim3(NB/4), dim3(256), 0, stream>>>(x, attW, attb, stats, uni, tw);
  k_gemm1<float><<<dim3(3*NB/128), dim3(256), 0, stream>>>(x, gfW1, UV1);
  k3_bi2<<<dim3(NB/8, 4), dim3(256), 0, stream>>>(UV1, gfW2, gfb1, gfb2, stats, avalvl);
  k3s_stats2<<<dim3(NB/4), dim3(256), 0, stream>>>(avalvl, x, stats, tw);
  k_gemm1<u16><<<dim3(3*NB/128), dim3(256), 0, stream>>>(avalvl, gfW1, UV2);
  k5_tri2<<<dim3(NB/8, 4), dim3(256), 0, stream>>>(UV2, UV1, gfW2, gfb1, gfb2, stats, tri);
  k6_final<<<dim3(NB/64), dim3(256), 0, stream>>>(uni, avalvl, tri, bng, bnb,
                                                  l1W, l1b, l2W, l2b, l3W, l3b, out);
}

// Round 2
// 1119.113 us; speedup vs baseline: 1.3395x; 1.3395x over previous
//
#include <hip/hip_runtime.h>
#include <math.h>

#define NB 16384
#define DD 1024
#define KF 5120   // concat feature K: uni(1024) + a_v,a_l,v_l(3*1024) + tri(1024)

typedef unsigned short u16;
typedef __attribute__((ext_vector_type(8))) short bf16x8;
typedef __attribute__((ext_vector_type(4))) float f32x4;

// ---------- helpers ----------
__device__ __forceinline__ float bf2f(u16 u){
  return __uint_as_float(((unsigned)u) << 16);
}
__device__ __forceinline__ u16 f2bf(float f){
  unsigned u = __float_as_uint(f);
  return (u16)((u + 0x7fffu + ((u >> 16) & 1u)) >> 16);   // RNE
}
__device__ __forceinline__ float wredsum(float x){
  #pragma unroll
  for(int o = 32; o >= 1; o >>= 1) x += __shfl_xor(x, o);
  return x;
}
__device__ __forceinline__ float wredmax(float x){
  #pragma unroll
  for(int o = 32; o >= 1; o >>= 1) x = fmaxf(x, __shfl_xor(x, o));
  return x;
}
__device__ __forceinline__ void load8(const float* p, float* o){
  float4 x0 = *(const float4*)p, x1 = *(const float4*)(p + 4);
  o[0]=x0.x;o[1]=x0.y;o[2]=x0.z;o[3]=x0.w;o[4]=x1.x;o[5]=x1.y;o[6]=x1.z;o[7]=x1.w;
}
__device__ __forceinline__ void load8(const u16* p, float* o){
  float4 raw = *(const float4*)p;           // 8 bf16 in 16B
  const u16* u = (const u16*)&raw;
  #pragma unroll
  for(int j = 0; j < 8; j++) o[j] = bf2f(u[j]);
}

// ---------- K1: per-row stats, w_uni, w_bi, unimodal ----------
__global__ __launch_bounds__(256) void k1_stats(
    const float* __restrict__ x, const float* __restrict__ attW,
    const float* __restrict__ attb, float* __restrict__ stats,
    u16* __restrict__ Fcat, float* __restrict__ tw)
{
  int wave = threadIdx.x >> 6, lane = threadIdx.x & 63;
  int r = blockIdx.x * 4 + wave;
  const float* xr = x + (size_t)r * 3 * DD;
  float a[16], v[16], l[16];
  float dA=0.f,dV=0.f,dL=0.f, mA=-1e30f,mV=-1e30f,mL=-1e30f;
  #pragma unroll
  for(int i = 0; i < 16; i++){
    int k = lane + i*64;
    a[i] = xr[k]; v[i] = xr[DD+k]; l[i] = xr[2*DD+k];
    float w = attW[k];
    dA = fmaf(a[i], w, dA); dV = fmaf(v[i], w, dV); dL = fmaf(l[i], w, dL);
    mA = fmaxf(mA, a[i]); mV = fmaxf(mV, v[i]); mL = fmaxf(mL, l[i]);
  }
  dA = wredsum(dA); dV = wredsum(dV); dL = wredsum(dL);
  mA = wredmax(mA); mV = wredmax(mV); mL = wredmax(mL);

  float Sa=0.f,Sv=0.f,Sl=0.f,Eav=0.f,Eal=0.f,Evl=0.f;
  #pragma unroll
  for(int i = 0; i < 16; i++){
    float ea = expf(a[i]-mA), ev = expf(v[i]-mV), el = expf(l[i]-mL);
    Sa += ea; Sv += ev; Sl += el;
    Eav += ea*ev; Eal += ea*el; Evl += ev*el;
  }
  Sa = wredsum(Sa); Sv = wredsum(Sv); Sl = wredsum(Sl);
  Eav = wredsum(Eav); Eal = wredsum(Eal); Evl = wredsum(Evl);

  float ab = attb[0];
  float ta = tanhf(dA + ab), tv = tanhf(dV + ab), tl = tanhf(dL + ab);
  float mm = fmaxf(ta, fmaxf(tv, tl));
  float e0 = expf(ta-mm), e1 = expf(tv-mm), e2 = expf(tl-mm);
  float ss = e0 + e1 + e2;
  float sa = e0/ss, sv = e1/ss, sl = e2/ss;
  float dav = Eav/(Sa*Sv), dal = Eal/(Sa*Sl), dvl = Evl/(Sv*Sl);
  float sav = (sa+sv)/(dav+0.5f);
  float sal = (sa+sl)/(dal+0.5f);
  float svl = (sv+sl)/(dvl+0.5f);
  float m2 = fmaxf(sav, fmaxf(sal, svl));
  float f0 = expf(sav-m2), f1 = expf(sal-m2), f2 = expf(svl-m2);
  float s2 = f0 + f1 + f2;
  float wb0 = f0/s2, wb1 = f1/s2, wb2 = f2/s2;

  if(lane == 0){
    float* st = stats + (size_t)r*24;
    st[0]=sa; st[1]=sv; st[2]=sl;
    st[3]=wb0; st[4]=wb1; st[5]=wb2;
    st[6]=sav; st[7]=sal; st[8]=svl;
    st[9]=mA; st[10]=Sa; st[11]=mV; st[12]=Sv; st[13]=mL; st[14]=Sl;
    float* twr = tw + (size_t)r*12;
    twr[0]=sa; twr[1]=sv; twr[2]=sl; twr[3]=wb0; twr[4]=wb1; twr[5]=wb2;
  }
  #pragma unroll
  for(int i = 0; i < 16; i++){
    int k = lane + i*64;
    Fcat[(size_t)r*KF + k] = f2bf((sa*a[i] + sv*v[i] + sl*l[i]) * (1.0f/3.0f));
  }
}

// ---------- K2/K4: layer-1 GEMM  (M,1024) @ Wcat(1024,128) ----------
template<typename T, int FCAT>
__global__ __launch_bounds__(256) void k_gemm1(
    const T* __restrict__ src, const float* __restrict__ W1,
    float* __restrict__ UV)
{
  __shared__ __align__(16) float As[16][132];
  __shared__ __align__(16) float Bs[16][132];
  int tid = threadIdx.x;
  int mb = blockIdx.x * 128;
  int ty = tid >> 4, tx = tid & 15;
  int r0 = ty * 8, c0 = tx * 8;
  int arow = tid >> 1, akoff = (tid & 1) * 8;
  int brow = tid >> 4, bcoff = (tid & 15) * 8;

  int m = mb + arow;
  size_t rbase;
  if(FCAT){ int R = m/3; rbase = (size_t)R*KF + (size_t)(1 + (m - 3*R))*1024; }
  else      rbase = (size_t)m*1024;

  float acc[8][8] = {};

  for(int k0 = 0; k0 < 1024; k0 += 16){
    float av8[8];
    load8(src + rbase + k0 + akoff, av8);
    #pragma unroll
    for(int j = 0; j < 8; j++) As[akoff + j][arow] = av8[j];
    {
      const float* p = (bcoff < 64)
          ? (W1 + (size_t)(k0 + brow)*64 + bcoff)
          : (W1 + (size_t)(1024 + k0 + brow)*64 + (bcoff - 64));
      float4 b0 = *(const float4*)p;
      float4 b1v = *(const float4*)(p + 4);
      *(float4*)&Bs[brow][bcoff]     = b0;
      *(float4*)&Bs[brow][bcoff + 4] = b1v;
    }
    __syncthreads();
    #pragma unroll
    for(int kk = 0; kk < 16; kk++){
      float ar[8], br[8];
      *(float4*)ar       = *(const float4*)&As[kk][r0];
      *(float4*)(ar + 4) = *(const float4*)&As[kk][r0 + 4];
      *(float4*)br       = *(const float4*)&Bs[kk][c0];
      *(float4*)(br + 4) = *(const float4*)&Bs[kk][c0 + 4];
      #pragma unroll
      for(int i = 0; i < 8; i++)
        #pragma unroll
        for(int j = 0; j < 8; j++)
          acc[i][j] = fmaf(ar[i], br[j], acc[i][j]);
    }
    __syncthreads();
  }
  #pragma unroll
  for(int i = 0; i < 8; i++){
    float* o = UV + (size_t)(mb + r0 + i)*128 + c0;
    *(float4*)o       = make_float4(acc[i][0],acc[i][1],acc[i][2],acc[i][3]);
    *(float4*)(o + 4) = make_float4(acc[i][4],acc[i][5],acc[i][6],acc[i][7]);
  }
}

// ---------- K3: layer-2 bimodal -> a_v, a_l, v_l into Fcat ----------
__global__ __launch_bounds__(256) void k3_bi2(
    const float* __restrict__ UV1, const float* __restrict__ W2,
    const float* __restrict__ b1, const float* __restrict__ b2,
    const float* __restrict__ stats, u16* __restrict__ Fcat)
{
  __shared__ __align__(16) float W2s[64][256];
  __shared__ float ts[8][3][64];
  int tid = threadIdx.x;
  int rb = blockIdx.x * 8;
  int cb = blockIdx.y * 256;

  #pragma unroll
  for(int t = 0; t < 16; t++){
    int f4 = tid + t*256;
    int kr = f4 >> 6, c4 = (f4 & 63) << 2;
    *(float4*)&W2s[kr][c4] = *(const float4*)&W2[(size_t)kr*DD + cb + c4];
  }
  #pragma unroll
  for(int t = 0; t < 6; t++){
    int f = tid + t*256;                 // 8*3*64 = 1536
    int rr = f / 192, rem = f % 192;
    int p = rem >> 6, j = rem & 63;
    int R = rb + rr;
    int up = (p == 2) ? 1 : 0;           // U source: a1,a1,v1
    int vp = (p == 0) ? 1 : 2;           // V source: v1,l1,l1
    float tv = UV1[(size_t)(3*R + up)*128 + j]
             + UV1[(size_t)(3*R + vp)*128 + 64 + j] + b1[j];
    ts[rr][p][j] = tv > 0.f ? tv : 0.2f*tv;
  }
  __syncthreads();

  int rr = tid >> 5;
  int c0 = (tid & 31) << 3;
  float acc[3][8] = {};
  #pragma unroll 4
  for(int kk = 0; kk < 64; kk++){
    float w8[8];
    *(float4*)w8       = *(const float4*)&W2s[kk][c0];
    *(float4*)(w8 + 4) = *(const float4*)&W2s[kk][c0 + 4];
    float t0 = ts[rr][0][kk], t1 = ts[rr][1][kk], t2 = ts[rr][2][kk];
    #pragma unroll
    for(int j = 0; j < 8; j++){
      acc[0][j] = fmaf(t0, w8[j], acc[0][j]);
      acc[1][j] = fmaf(t1, w8[j], acc[1][j]);
      acc[2][j] = fmaf(t2, w8[j], acc[2][j]);
    }
  }
  int R = rb + rr;
  const float* st = stats + (size_t)R*24;
  #pragma unroll
  for(int p = 0; p < 3; p++){
    float wbp = st[3 + p];
    __align__(16) u16 o8[8];
    #pragma unroll
    for(int j = 0; j < 8; j++){
      int c = cb + c0 + j;
      float g = tanhf(acc[p][j] + b2[c]);
      float val = wbp * g;
      o8[j] = f2bf(val > 0.f ? val : 0.01f*val);
    }
    *(float4*)&Fcat[(size_t)R*KF + (size_t)(1+p)*1024 + cb + c0] = *(float4*)o8;
  }
}

// ---------- K3s: softmax stats of a_v/a_l/v_l + cross dots -> w_tri ----------
__global__ __launch_bounds__(256) void k3s_stats2(
    const u16* __restrict__ Fcat, const float* __restrict__ x,
    float* __restrict__ stats, float* __restrict__ tw)
{
  int wave = threadIdx.x >> 6, lane = threadIdx.x & 63;
  int r = blockIdx.x * 4 + wave;
  const u16*   pv = Fcat + (size_t)r*KF + 1024;
  const float* xr = x    + (size_t)3*r*DD;
  float av[16], al[16], vl[16];
  float mav=-1e30f, mal=-1e30f, mvl=-1e30f;
  #pragma unroll
  for(int i = 0; i < 16; i++){
    int k = lane + i*64;
    av[i] = bf2f(pv[k]); al[i] = bf2f(pv[DD+k]); vl[i] = bf2f(pv[2*DD+k]);
    mav = fmaxf(mav, av[i]); mal = fmaxf(mal, al[i]); mvl = fmaxf(mvl, vl[i]);
  }
  mav = wredmax(mav); mal = wredmax(mal); mvl = wredmax(mvl);

  float* st = stats + (size_t)r*24;
  float sa=st[0], sv=st[1], sl=st[2];
  float sav=st[6], sal=st[7], svl=st[8];
  float mA=st[9], Sa=st[10], mV=st[11], Sv=st[12], mL=st[13], Sl=st[14];

  float Savv=0.f,Sall=0.f,Svll=0.f,E1=0.f,E2=0.f,E3=0.f,E4=0.f,E5=0.f,E6=0.f;
  #pragma unroll
  for(int i = 0; i < 16; i++){
    int k = lane + i*64;
    float a1 = xr[k], v1 = xr[DD+k], l1 = xr[2*DD+k];
    float eav = expf(av[i]-mav), eal = expf(al[i]-mal), evl = expf(vl[i]-mvl);
    Savv += eav; Sall += eal; Svll += evl;
    float ea = expf(a1-mA), ev = expf(v1-mV), el = expf(l1-mL);
    E1 += eav*evl; E2 += eav*eal; E3 += eal*evl;
    E4 += eav*el;  E5 += eal*ev;  E6 += evl*ea;
  }
  Savv = wredsum(Savv); Sall = wredsum(Sall); Svll = wredsum(Svll);
  E1 = wredsum(E1); E2 = wredsum(E2); E3 = wredsum(E3);
  E4 = wredsum(E4); E5 = wredsum(E5); E6 = wredsum(E6);

  float d1 = E1/(Savv*Svll), d2 = E2/(Savv*Sall), d3 = E3/(Sall*Svll);
  float d4 = E4/(Savv*Sl),   d5 = E5/(Sall*Sv),   d6 = E6/(Svll*Sa);
  float t0 = (sav+svl)/(d1+0.5f);
  float t1 = (sav+sal)/(d2+0.5f);
  float t2 = (sal+svl)/(d3+0.5f);
  float t3 = (sav+sl)/(d4+0.5f);
  float t4 = (sal+sv)/(d5+0.5f);
  float t5 = (sa+svl)/(d6+0.5f);
  float mx = fmaxf(fmaxf(fmaxf(t0,t1),fmaxf(t2,t3)),fmaxf(t4,t5));
  float g0=expf(t0-mx),g1=expf(t1-mx),g2=expf(t2-mx);
  float g3=expf(t3-mx),g4=expf(t4-mx),g5=expf(t5-mx);
  float gs = g0+g1+g2+g3+g4+g5;
  if(lane == 0){
    float wt[6] = {g0/gs,g1/gs,g2/gs,g3/gs,g4/gs,g5/gs};
    float* twr = tw + (size_t)r*12;
    #pragma unroll
    for(int p = 0; p < 6; p++){ st[15+p] = wt[p]; twr[6+p] = wt[p]; }
  }
}

// ---------- K5: layer-2 trimodal -> tri into Fcat ----------
__global__ __launch_bounds__(256) void k5_tri2(
    const float* __restrict__ UV2, const float* __restrict__ UV1,
    const float* __restrict__ W2, const float* __restrict__ b1,
    const float* __restrict__ b2, const float* __restrict__ stats,
    u16* __restrict__ Fcat)
{
  __shared__ __align__(16) float W2s[64][256];
  __shared__ float ts[8][6][64];
  int tid = threadIdx.x;
  int rb = blockIdx.x * 8;
  int cb = blockIdx.y * 256;

  #pragma unroll
  for(int t = 0; t < 16; t++){
    int f4 = tid + t*256;
    int kr = f4 >> 6, c4 = (f4 & 63) << 2;
    *(float4*)&W2s[kr][c4] = *(const float4*)&W2[(size_t)kr*DD + cb + c4];
  }
  #pragma unroll
  for(int t = 0; t < 12; t++){
    int f = tid + t*256;                  // 8*6*64 = 3072
    int rr = f / 384, rem = f % 384;
    int p = rem >> 6, j = rem & 63;
    int R = rb + rr;
    int up = (0x210200 >> (p*4)) & 15;    // a_v,a_v,v_l,a_v,a_l,v_l
    int vp = (0x012112 >> (p*4)) & 15;    // v_l,a_l,a_l,l1,v1,a1
    const float* VB = (p < 3) ? UV2 : UV1;
    float tv = UV2[(size_t)(3*R + up)*128 + j]
             + VB[(size_t)(3*R + vp)*128 + 64 + j] + b1[j];
    ts[rr][p][j] = tv > 0.f ? tv : 0.2f*tv;
  }
  __syncthreads();

  int rr = tid >> 5;
  int c0 = (tid & 31) << 3;
  float acc[6][8] = {};
  #pragma unroll 4
  for(int kk = 0; kk < 64; kk++){
    float w8[8];
    *(float4*)w8       = *(const float4*)&W2s[kk][c0];
    *(float4*)(w8 + 4) = *(const float4*)&W2s[kk][c0 + 4];
    float tv[6];
    #pragma unroll
    for(int p = 0; p < 6; p++) tv[p] = ts[rr][p][kk];
    #pragma unroll
    for(int p = 0; p < 6; p++)
      #pragma unroll
      for(int j = 0; j < 8; j++)
        acc[p][j] = fmaf(tv[p], w8[j], acc[p][j]);
  }
  int R = rb + rr;
  const float* st = stats + (size_t)R*24;
  float wt[6];
  #pragma unroll
  for(int p = 0; p < 6; p++) wt[p] = st[15+p];
  __align__(16) u16 o8[8];
  #pragma unroll
  for(int j = 0; j < 8; j++){
    int c = cb + c0 + j;
    float b2c = b2[c];
    float sum = 0.f;
    #pragma unroll
    for(int p = 0; p < 6; p++){
      float g = tanhf(acc[p][j] + b2c);
      float val = wt[p] * g;
      sum += val > 0.f ? val : 0.01f*val;
    }
    o8[j] = f2bf(sum * (1.0f/6.0f));
  }
  *(float4*)&Fcat[(size_t)R*KF + 4096 + cb + c0] = *(float4*)o8;
}

// ---------- K6 precompute: WpT (64 x 5120 bf16), BN folded ----------
__global__ __launch_bounds__(256) void k6_prew(
    const float* __restrict__ gamma, const float* __restrict__ l1W,
    u16* __restrict__ WpT)
{
  int kk = blockIdx.x * 256 + threadIdx.x;   // 0..5119 (grid.x = 20)
  int j  = blockIdx.y;                        // 0..63
  const float gsc = 1.0f / sqrtf(1.0f + 1e-5f);
  int korig; float sc;
  if(kk < 1024){ korig = kk; sc = 1.f; }
  else if(kk < 4096){ korig = 1024 + ((kk - 1024) & 1023); sc = 1.0f/3.0f; }
  else { korig = 2048 + (kk - 4096); sc = 1.f; }
  float v = (j < 50) ? l1W[(size_t)korig*50 + j] * gamma[korig] * gsc * sc : 0.f;
  WpT[(size_t)j*KF + kk] = f2bf(v);
}

// ---------- K6 precompute: bp[j] = l1b[j] + beta @ l1W ----------
__global__ __launch_bounds__(256) void k6_preb(
    const float* __restrict__ beta, const float* __restrict__ l1W,
    const float* __restrict__ l1b, float* __restrict__ bp)
{
  __shared__ float red[4][64];
  int j = threadIdx.x & 63, seg = threadIdx.x >> 6;
  float s = 0.f;
  if(j < 50){
    for(int k = seg*768; k < seg*768 + 768; k++)
      s = fmaf(beta[k], l1W[(size_t)k*50 + j], s);
  }
  red[seg][j] = s;
  __syncthreads();
  if(seg == 0){
    float t = red[0][j] + red[1][j] + red[2][j] + red[3][j];
    bp[j] = (j < 50) ? (l1b[j] + t) : 0.f;
  }
}

// ---------- K6: MFMA GEMM (NB x 5120)@(5120 x 64) + MLP tail + softmax ----------
__global__ __launch_bounds__(256) void k6_mfma(
    const u16* __restrict__ Fcat, const u16* __restrict__ WpT,
    const float* __restrict__ bp,
    const float* __restrict__ l2W, const float* __restrict__ l2b,
    const float* __restrict__ l3W, const float* __restrict__ l3b,
    float* __restrict__ y2out)
{
  __shared__ float Ys[64][68];
  __shared__ float W2s[50][52];
  __shared__ float W3s[50][8];
  __shared__ float Ys2[64][52];

  int tid = threadIdx.x;
  int wv = tid >> 6, lane = tid & 63;
  int rb = blockIdx.x * 64;
  int r0 = rb + wv * 16;

  // stage small weights (consumed after the post-MFMA barrier)
  for(int t = tid; t < 50*52; t += 256)
    W2s[t/52][t%52] = (t%52 < 50) ? l2W[(t/52)*50 + (t%52)] : 0.f;
  for(int t = tid; t < 400; t += 256)
    W3s[t/8][t%8] = l3W[t];

  int fr = lane & 15, kg = lane >> 4;     // fragment row / k-group
  const u16* aptr = Fcat + (size_t)(r0 + fr) * KF + kg * 8;
  const u16* bp0  = WpT + (size_t)fr * KF + kg * 8;
  const u16* bp1  = bp0 + (size_t)16 * KF;
  const u16* bp2  = bp0 + (size_t)32 * KF;
  const u16* bp3  = bp0 + (size_t)48 * KF;

  f32x4 acc0 = {0,0,0,0}, acc1 = {0,0,0,0}, acc2 = {0,0,0,0}, acc3 = {0,0,0,0};
  for(int k0 = 0; k0 < KF; k0 += 64){
    bf16x8 a0 = *(const bf16x8*)(aptr + k0);
    bf16x8 a1 = *(const bf16x8*)(aptr + k0 + 32);
    bf16x8 b00 = *(const bf16x8*)(bp0 + k0), b01 = *(const bf16x8*)(bp0 + k0 + 32);
    bf16x8 b10 = *(const bf16x8*)(bp1 + k0), b11 = *(const bf16x8*)(bp1 + k0 + 32);
    bf16x8 b20 = *(const bf16x8*)(bp2 + k0), b21 = *(const bf16x8*)(bp2 + k0 + 32);
    bf16x8 b30 = *(const bf16x8*)(bp3 + k0), b31 = *(const bf16x8*)(bp3 + k0 + 32);
    acc0 = __builtin_amdgcn_mfma_f32_16x16x32_bf16(a0, b00, acc0, 0, 0, 0);
    acc1 = __builtin_amdgcn_mfma_f32_16x16x32_bf16(a0, b10, acc1, 0, 0, 0);
    acc2 = __builtin_amdgcn_mfma_f32_16x16x32_bf16(a0, b20, acc2, 0, 0, 0);
    acc3 = __builtin_amdgcn_mfma_f32_16x16x32_bf16(a0, b30, acc3, 0, 0, 0);
    acc0 = __builtin_amdgcn_mfma_f32_16x16x32_bf16(a1, b01, acc0, 0, 0, 0);
    acc1 = __builtin_amdgcn_mfma_f32_16x16x32_bf16(a1, b11, acc1, 0, 0, 0);
    acc2 = __builtin_amdgcn_mfma_f32_16x16x32_bf16(a1, b21, acc2, 0, 0, 0);
    acc3 = __builtin_amdgcn_mfma_f32_16x16x32_bf16(a1, b31, acc3, 0, 0, 0);
  }

  // epilogue: y1 = tanh(acc + bp) -> Ys   (D: row=(lane>>4)*4+q, col=lane&15)
  {
    int rr = wv*16 + kg*4;
    #pragma unroll
    for(int q = 0; q < 4; q++){
      if(fr      < 50) Ys[rr+q][fr]      = tanhf(acc0[q] + bp[fr]);
      if(fr + 16 < 50) Ys[rr+q][fr + 16] = tanhf(acc1[q] + bp[fr + 16]);
      if(fr + 32 < 50) Ys[rr+q][fr + 32] = tanhf(acc2[q] + bp[fr + 32]);
      // cols 48..63: only 48,49 valid (from acc3)
      if(fr + 48 < 50) Ys[rr+q][fr + 48] = tanhf(acc3[q] + bp[fr + 48]);
    }
  }
  __syncthreads();

  // stage 2: Ys(64x50) @ W2s(50x50) -> tanh -> Ys2
  {
    int row = tid >> 2, qq = tid & 3;
    int cbeg = qq * 13;
    float a2[13];
    #pragma unroll
    for(int c = 0; c < 13; c++) a2[c] = 0.f;
    for(int kk = 0; kk < 50; kk++){
      float yv = Ys[row][kk];
      #pragma unroll
      for(int c = 0; c < 13; c++)
        a2[c] = fmaf(yv, W2s[kk][cbeg + c], a2[c]);
    }
    #pragma unroll
    for(int c = 0; c < 13; c++){
      int cc = cbeg + c;
      if(cc < 50) Ys2[row][cc] = tanhf(a2[c] + l2b[cc]);
    }
  }
  __syncthreads();

  // stage 3: Ys2(64x50) @ W3s(50x8) + b3, softmax over 8
  {
    int row = tid >> 2, q3 = tid & 3;
    int ca = 2*q3, cb2 = 2*q3 + 1;
    float z0 = l3b[ca], z1 = l3b[cb2];
    for(int kk = 0; kk < 50; kk++){
      float yv = Ys2[row][kk];
      z0 = fmaf(yv, W3s[kk][ca], z0);
      z1 = fmaf(yv, W3s[kk][cb2], z1);
    }
    float m = fmaxf(z0, z1);
    m = fmaxf(m, __shfl_xor(m, 1));
    m = fmaxf(m, __shfl_xor(m, 2));
    float e0 = expf(z0 - m), e1 = expf(z1 - m);
    float s = e0 + e1;
    s += __shfl_xor(s, 1);
    s += __shfl_xor(s, 2);
    int R = rb + row;
    y2out[(size_t)R*8 + ca]  = e0 / s;
    y2out[(size_t)R*8 + cb2] = e1 / s;
  }
}

// ---------- launch ----------
extern "C" void kernel_launch(void* const* d_in, const int* in_sizes, int n_in,
                              void* d_out, int out_size, void* d_ws, size_t ws_size,
                              hipStream_t stream)
{
  (void)in_sizes; (void)n_in; (void)out_size; (void)ws_size;
  const float* x    = (const float*)d_in[0];
  const float* attW = (const float*)d_in[1];
  const float* attb = (const float*)d_in[2];
  const float* gfW1 = (const float*)d_in[3];
  const float* gfb1 = (const float*)d_in[4];
  const float* gfW2 = (const float*)d_in[5];
  const float* gfb2 = (const float*)d_in[6];
  const float* bng  = (const float*)d_in[7];
  const float* bnb  = (const float*)d_in[8];
  const float* l1W  = (const float*)d_in[9];
  const float* l1b  = (const float*)d_in[10];
  const float* l2W  = (const float*)d_in[11];
  const float* l2b  = (const float*)d_in[12];
  const float* l3W  = (const float*)d_in[13];
  const float* l3b  = (const float*)d_in[14];

  float* out = (float*)d_out;
  float* tw  = out + (size_t)NB*8;

  // workspace layout (~221 MB)
  float* ws    = (float*)d_ws;
  float* stats = ws;                               // NB*24 f32
  float* UV1   = stats + (size_t)NB*24;            // 3*NB*128 f32
  float* UV2   = UV1 + (size_t)3*NB*128;           // 3*NB*128 f32
  float* bp    = UV2 + (size_t)3*NB*128;           // 64 f32
  u16* WpT     = (u16*)(bp + 64);                  // 64*KF bf16
  u16* Fcat    = WpT + (size_t)64*KF;              // NB*KF bf16

  k1_stats<<<dim3(NB/4), dim3(256), 0, stream>>>(x, attW, attb, stats, Fcat, tw);
  k_gemm1<float,0><<<dim3(3*NB/128), dim3(256), 0, stream>>>(x, gfW1, UV1);
  k3_bi2<<<dim3(NB/8, 4), dim3(256), 0, stream>>>(UV1, gfW2, gfb1, gfb2, stats, Fcat);
  k3s_stats2<<<dim3(NB/4), dim3(256), 0, stream>>>(Fcat, x, stats, tw);
  k_gemm1<u16,1><<<dim3(3*NB/128), dim3(256), 0, stream>>>(Fcat, gfW1, UV2);
  k5_tri2<<<dim3(NB/8, 4), dim3(256), 0, stream>>>(UV2, UV1, gfW2, gfb1, gfb2, stats, Fcat);
  k6_prew<<<dim3(20, 64), dim3(256), 0, stream>>>(bng, l1W, WpT);
  k6_preb<<<dim3(1), dim3(256), 0, stream>>>(bnb, l1W, l1b, bp);
  k6_mfma<<<dim3(NB/64), dim3(256), 0, stream>>>(Fcat, WpT, bp, l2W, l2b, l3W, l3b, out);
}

// Round 3
// 668.103 us; speedup vs baseline: 2.2438x; 1.6751x over previous
//
#include <hip/hip_runtime.h>
#include <math.h>

#define NB 16384
#define DD 1024
#define KF 5120   // concat feature K: uni(1024) + a_v,a_l,v_l(3*1024) + tri(1024)

typedef unsigned short u16;
typedef __attribute__((ext_vector_type(8))) short bf16x8;
typedef __attribute__((ext_vector_type(4))) float f32x4;

// ---------- helpers ----------
__device__ __forceinline__ float bf2f(u16 u){
  return __uint_as_float(((unsigned)u) << 16);
}
__device__ __forceinline__ u16 f2bf(float f){
  unsigned u = __float_as_uint(f);
  return (u16)((u + 0x7fffu + ((u >> 16) & 1u)) >> 16);   // RNE
}
__device__ __forceinline__ float fast_tanh(float x){
  float e = __expf(2.0f * x);
  return 1.0f - 2.0f / (e + 1.0f);
}
__device__ __forceinline__ float wredsum(float x){
  #pragma unroll
  for(int o = 32; o >= 1; o >>= 1) x += __shfl_xor(x, o);
  return x;
}
__device__ __forceinline__ float wredmax(float x){
  #pragma unroll
  for(int o = 32; o >= 1; o >>= 1) x = fmaxf(x, __shfl_xor(x, o));
  return x;
}
__device__ __forceinline__ bf16x8 pack8f(float4 f0, float4 f1){
  bf16x8 r;
  r[0]=(short)f2bf(f0.x); r[1]=(short)f2bf(f0.y); r[2]=(short)f2bf(f0.z); r[3]=(short)f2bf(f0.w);
  r[4]=(short)f2bf(f1.x); r[5]=(short)f2bf(f1.y); r[6]=(short)f2bf(f1.z); r[7]=(short)f2bf(f1.w);
  return r;
}

// ---------- K1: per-row stats, w_uni, w_bi, unimodal ----------
__global__ __launch_bounds__(256) void k1_stats(
    const float* __restrict__ x, const float* __restrict__ attW,
    const float* __restrict__ attb, float* __restrict__ stats,
    u16* __restrict__ Fcat, float* __restrict__ tw)
{
  int wave = threadIdx.x >> 6, lane = threadIdx.x & 63;
  int r = blockIdx.x * 4 + wave;
  const float* xr = x + (size_t)r * 3 * DD;
  float a[16], v[16], l[16];
  float dA=0.f,dV=0.f,dL=0.f, mA=-1e30f,mV=-1e30f,mL=-1e30f;
  #pragma unroll
  for(int i = 0; i < 16; i++){
    int k = lane + i*64;
    a[i] = xr[k]; v[i] = xr[DD+k]; l[i] = xr[2*DD+k];
    float w = attW[k];
    dA = fmaf(a[i], w, dA); dV = fmaf(v[i], w, dV); dL = fmaf(l[i], w, dL);
    mA = fmaxf(mA, a[i]); mV = fmaxf(mV, v[i]); mL = fmaxf(mL, l[i]);
  }
  dA = wredsum(dA); dV = wredsum(dV); dL = wredsum(dL);
  mA = wredmax(mA); mV = wredmax(mV); mL = wredmax(mL);

  float Sa=0.f,Sv=0.f,Sl=0.f,Eav=0.f,Eal=0.f,Evl=0.f;
  #pragma unroll
  for(int i = 0; i < 16; i++){
    float ea = __expf(a[i]-mA), ev = __expf(v[i]-mV), el = __expf(l[i]-mL);
    Sa += ea; Sv += ev; Sl += el;
    Eav += ea*ev; Eal += ea*el; Evl += ev*el;
  }
  Sa = wredsum(Sa); Sv = wredsum(Sv); Sl = wredsum(Sl);
  Eav = wredsum(Eav); Eal = wredsum(Eal); Evl = wredsum(Evl);

  float ab = attb[0];
  float ta = fast_tanh(dA + ab), tv = fast_tanh(dV + ab), tl = fast_tanh(dL + ab);
  float mm = fmaxf(ta, fmaxf(tv, tl));
  float e0 = __expf(ta-mm), e1 = __expf(tv-mm), e2 = __expf(tl-mm);
  float ss = e0 + e1 + e2;
  float sa = e0/ss, sv = e1/ss, sl = e2/ss;
  float dav = Eav/(Sa*Sv), dal = Eal/(Sa*Sl), dvl = Evl/(Sv*Sl);
  float sav = (sa+sv)/(dav+0.5f);
  float sal = (sa+sl)/(dal+0.5f);
  float svl = (sv+sl)/(dvl+0.5f);
  float m2 = fmaxf(sav, fmaxf(sal, svl));
  float f0 = __expf(sav-m2), f1 = __expf(sal-m2), f2 = __expf(svl-m2);
  float s2 = f0 + f1 + f2;
  float wb0 = f0/s2, wb1 = f1/s2, wb2 = f2/s2;

  if(lane == 0){
    float* st = stats + (size_t)r*24;
    st[0]=sa; st[1]=sv; st[2]=sl;
    st[3]=wb0; st[4]=wb1; st[5]=wb2;
    st[6]=sav; st[7]=sal; st[8]=svl;
    st[9]=mA; st[10]=Sa; st[11]=mV; st[12]=Sv; st[13]=mL; st[14]=Sl;
    float* twr = tw + (size_t)r*12;
    twr[0]=sa; twr[1]=sv; twr[2]=sl; twr[3]=wb0; twr[4]=wb1; twr[5]=wb2;
  }
  #pragma unroll
  for(int i = 0; i < 16; i++){
    int k = lane + i*64;
    Fcat[(size_t)r*KF + k] = f2bf((sa*a[i] + sv*v[i] + sl*l[i]) * (1.0f/3.0f));
  }
}

// ---------- precompute: Wb1 (128 x 1024 bf16): [n][k], n<64 -> U cols, else V ----------
__global__ __launch_bounds__(256) void kprew_b1(
    const float* __restrict__ W1, u16* __restrict__ Wb1)
{
  int idx = blockIdx.x * 256 + threadIdx.x;   // 0..131071
  int n = idx >> 10, k = idx & 1023;
  float v = (n < 64) ? W1[(size_t)k*64 + n] : W1[(size_t)(1024+k)*64 + (n-64)];
  Wb1[idx] = f2bf(v);
}

// ---------- precompute: W2T (1024 x 64 bf16): [c][k] = W2[k][c] ----------
__global__ __launch_bounds__(256) void kprew_w2t(
    const float* __restrict__ W2, u16* __restrict__ W2T)
{
  int idx = blockIdx.x * 256 + threadIdx.x;   // 0..65535
  int c = idx >> 6, k = idx & 63;
  W2T[idx] = f2bf(W2[(size_t)k*DD + c]);
}

// ---------- layer-1 MFMA GEMM: (3NB,1024) @ Wb1^T -> UV (3NB x 128 fp32) ----------
template<int FROM_X>
__global__ __launch_bounds__(256) void kg1_mfma(
    const float* __restrict__ xf, const u16* __restrict__ fc,
    const u16* __restrict__ Wb1, float* __restrict__ UV)
{
  int tid = threadIdx.x;
  int wv = tid >> 6, lane = tid & 63;
  int fr = lane & 15, kg = lane >> 4;
  int m = blockIdx.x * 64 + wv * 16 + fr;   // A row
  size_t abase;
  if(FROM_X) abase = (size_t)m * 1024;
  else { int R = m/3; abase = (size_t)R*KF + (size_t)(1 + (m - 3*R))*1024; }
  const u16* bbase = Wb1 + (size_t)fr * 1024 + kg * 8;

  f32x4 zero = {0.f,0.f,0.f,0.f};
  f32x4 acc[8];
  #pragma unroll
  for(int cf = 0; cf < 8; cf++) acc[cf] = zero;

  for(int k0 = 0; k0 < 1024; k0 += 64){
    bf16x8 a0, a1;
    if(FROM_X){
      const float* ap = xf + abase + k0 + kg*8;
      a0 = pack8f(*(const float4*)ap,      *(const float4*)(ap+4));
      a1 = pack8f(*(const float4*)(ap+32), *(const float4*)(ap+36));
    } else {
      const u16* ap = fc + abase + k0 + kg*8;
      a0 = *(const bf16x8*)ap;
      a1 = *(const bf16x8*)(ap + 32);
    }
    #pragma unroll
    for(int cf = 0; cf < 8; cf++){
      bf16x8 b0 = *(const bf16x8*)(bbase + (size_t)(cf*16)*1024 + k0);
      bf16x8 b1 = *(const bf16x8*)(bbase + (size_t)(cf*16)*1024 + k0 + 32);
      acc[cf] = __builtin_amdgcn_mfma_f32_16x16x32_bf16(a0, b0, acc[cf], 0, 0, 0);
      acc[cf] = __builtin_amdgcn_mfma_f32_16x16x32_bf16(a1, b1, acc[cf], 0, 0, 0);
    }
  }
  int rowb = blockIdx.x * 64 + wv * 16 + kg * 4;
  #pragma unroll
  for(int cf = 0; cf < 8; cf++)
    #pragma unroll
    for(int q = 0; q < 4; q++)
      UV[(size_t)(rowb + q)*128 + cf*16 + fr] = acc[cf][q];
}

// ---------- T-stage bi: T[p][R][64] = lrelu0.2(U1[up]+V1[vp]+b1), p=0..2 ----------
__global__ __launch_bounds__(256) void kT_bi(
    const float* __restrict__ UV1, const float* __restrict__ b1,
    u16* __restrict__ T)
{
  int g = blockIdx.x * 256 + threadIdx.x;   // 3*NB*8 groups of 8 elems
  int j8 = (g & 7) * 8;
  int m = g >> 3;                           // p*NB + R
  int p = m >> 14, R = m & (NB-1);
  int up = (p == 2) ? 1 : 0;
  int vp = (p == 0) ? 1 : 2;
  const float* Up = UV1 + (size_t)(3*R + up)*128 + j8;
  const float* Vp = UV1 + (size_t)(3*R + vp)*128 + 64 + j8;
  float4 u0 = *(const float4*)Up, u1 = *(const float4*)(Up+4);
  float4 v0 = *(const float4*)Vp, v1 = *(const float4*)(Vp+4);
  const float4 bb0 = *(const float4*)(b1 + j8), bb1 = *(const float4*)(b1 + j8 + 4);
  float t[8] = {u0.x+v0.x+bb0.x, u0.y+v0.y+bb0.y, u0.z+v0.z+bb0.z, u0.w+v0.w+bb0.w,
                u1.x+v1.x+bb1.x, u1.y+v1.y+bb1.y, u1.z+v1.z+bb1.z, u1.w+v1.w+bb1.w};
  bf16x8 o;
  #pragma unroll
  for(int j = 0; j < 8; j++){
    float tv = t[j] > 0.f ? t[j] : 0.2f*t[j];
    o[j] = (short)f2bf(tv);
  }
  *(bf16x8*)&T[(size_t)m*64 + j8] = o;
}

// ---------- T-stage tri: p=0..5, U from UV2, V from UV2 (p<3) or UV1 ----------
__global__ __launch_bounds__(256) void kT_tri(
    const float* __restrict__ UV2, const float* __restrict__ UV1,
    const float* __restrict__ b1, u16* __restrict__ T)
{
  int g = blockIdx.x * 256 + threadIdx.x;   // 6*NB*8 groups
  int j8 = (g & 7) * 8;
  int m = g >> 3;                           // p*NB + R
  int p = m >> 14, R = m & (NB-1);
  int up = (0x210200 >> (p*4)) & 15;        // a_v,a_v,v_l,a_v,a_l,v_l
  int vp = (0x012112 >> (p*4)) & 15;        // v_l,a_l,a_l,l1,v1,a1
  const float* VB = (p < 3) ? UV2 : UV1;
  const float* Up = UV2 + (size_t)(3*R + up)*128 + j8;
  const float* Vp = VB  + (size_t)(3*R + vp)*128 + 64 + j8;
  float4 u0 = *(const float4*)Up, u1 = *(const float4*)(Up+4);
  float4 v0 = *(const float4*)Vp, v1 = *(const float4*)(Vp+4);
  const float4 bb0 = *(const float4*)(b1 + j8), bb1 = *(const float4*)(b1 + j8 + 4);
  float t[8] = {u0.x+v0.x+bb0.x, u0.y+v0.y+bb0.y, u0.z+v0.z+bb0.z, u0.w+v0.w+bb0.w,
                u1.x+v1.x+bb1.x, u1.y+v1.y+bb1.y, u1.z+v1.z+bb1.z, u1.w+v1.w+bb1.w};
  bf16x8 o;
  #pragma unroll
  for(int j = 0; j < 8; j++){
    float tv = t[j] > 0.f ? t[j] : 0.2f*t[j];
    o[j] = (short)f2bf(tv);
  }
  *(bf16x8*)&T[(size_t)m*64 + j8] = o;
}

// ---------- layer-2 MFMA: T[p] @ W2 + epilogue -> Fcat slices ----------
// block: 16 rows x 256 cols, 4 waves (one 64-col group each), P pairs in-register.
template<int P, int SUM>
__global__ __launch_bounds__(256) void kL2_mfma(
    const u16* __restrict__ T, const u16* __restrict__ W2T,
    const float* __restrict__ b2, const float* __restrict__ stats,
    u16* __restrict__ Fcat)
{
  int tid = threadIdx.x;
  int wv = tid >> 6, lane = tid & 63;
  int fr = lane & 15, kg = lane >> 4;
  int Rb = blockIdx.x * 16;
  int cb = blockIdx.y * 256 + wv * 64;

  f32x4 zero = {0.f,0.f,0.f,0.f};
  f32x4 acc[P][4];
  #pragma unroll
  for(int p = 0; p < P; p++)
    #pragma unroll
    for(int cf = 0; cf < 4; cf++) acc[p][cf] = zero;

  #pragma unroll
  for(int ks = 0; ks < 2; ks++){
    bf16x8 a[P];
    #pragma unroll
    for(int p = 0; p < P; p++)
      a[p] = *(const bf16x8*)&T[(size_t)(p*NB + Rb + fr)*64 + ks*32 + kg*8];
    #pragma unroll
    for(int cf = 0; cf < 4; cf++){
      bf16x8 b = *(const bf16x8*)&W2T[(size_t)(cb + cf*16 + fr)*64 + ks*32 + kg*8];
      #pragma unroll
      for(int p = 0; p < P; p++)
        acc[p][cf] = __builtin_amdgcn_mfma_f32_16x16x32_bf16(a[p], b, acc[p][cf], 0, 0, 0);
    }
  }

  #pragma unroll
  for(int q = 0; q < 4; q++){
    int R = Rb + kg*4 + q;
    const float* st = stats + (size_t)R*24;
    #pragma unroll
    for(int cf = 0; cf < 4; cf++){
      int c = cb + cf*16 + fr;
      float b2c = b2[c];
      if(SUM){
        float s = 0.f;
        #pragma unroll
        for(int p = 0; p < P; p++){
          float g = st[15+p] * fast_tanh(acc[p][cf][q] + b2c);
          s += g > 0.f ? g : 0.01f*g;
        }
        Fcat[(size_t)R*KF + 4096 + c] = f2bf(s * (1.0f/6.0f));
      } else {
        #pragma unroll
        for(int p = 0; p < P; p++){
          float g = st[3+p] * fast_tanh(acc[p][cf][q] + b2c);
          float val = g > 0.f ? g : 0.01f*g;
          Fcat[(size_t)R*KF + (size_t)(1+p)*1024 + c] = f2bf(val);
        }
      }
    }
  }
}

// ---------- K3s: softmax stats of a_v/a_l/v_l + cross dots -> w_tri ----------
__global__ __launch_bounds__(256) void k3s_stats2(
    const u16* __restrict__ Fcat, const float* __restrict__ x,
    float* __restrict__ stats, float* __restrict__ tw)
{
  int wave = threadIdx.x >> 6, lane = threadIdx.x & 63;
  int r = blockIdx.x * 4 + wave;
  const u16*   pv = Fcat + (size_t)r*KF + 1024;
  const float* xr = x    + (size_t)3*r*DD;
  float av[16], al[16], vl[16];
  float mav=-1e30f, mal=-1e30f, mvl=-1e30f;
  #pragma unroll
  for(int i = 0; i < 16; i++){
    int k = lane + i*64;
    av[i] = bf2f(pv[k]); al[i] = bf2f(pv[DD+k]); vl[i] = bf2f(pv[2*DD+k]);
    mav = fmaxf(mav, av[i]); mal = fmaxf(mal, al[i]); mvl = fmaxf(mvl, vl[i]);
  }
  mav = wredmax(mav); mal = wredmax(mal); mvl = wredmax(mvl);

  float* st = stats + (size_t)r*24;
  float sa=st[0], sv=st[1], sl=st[2];
  float sav=st[6], sal=st[7], svl=st[8];
  float mA=st[9], Sa=st[10], mV=st[11], Sv=st[12], mL=st[13], Sl=st[14];

  float Savv=0.f,Sall=0.f,Svll=0.f,E1=0.f,E2=0.f,E3=0.f,E4=0.f,E5=0.f,E6=0.f;
  #pragma unroll
  for(int i = 0; i < 16; i++){
    int k = lane + i*64;
    float a1 = xr[k], v1 = xr[DD+k], l1 = xr[2*DD+k];
    float eav = __expf(av[i]-mav), eal = __expf(al[i]-mal), evl = __expf(vl[i]-mvl);
    Savv += eav; Sall += eal; Svll += evl;
    float ea = __expf(a1-mA), ev = __expf(v1-mV), el = __expf(l1-mL);
    E1 += eav*evl; E2 += eav*eal; E3 += eal*evl;
    E4 += eav*el;  E5 += eal*ev;  E6 += evl*ea;
  }
  Savv = wredsum(Savv); Sall = wredsum(Sall); Svll = wredsum(Svll);
  E1 = wredsum(E1); E2 = wredsum(E2); E3 = wredsum(E3);
  E4 = wredsum(E4); E5 = wredsum(E5); E6 = wredsum(E6);

  float d1 = E1/(Savv*Svll), d2 = E2/(Savv*Sall), d3 = E3/(Sall*Svll);
  float d4 = E4/(Savv*Sl),   d5 = E5/(Sall*Sv),   d6 = E6/(Svll*Sa);
  float t0 = (sav+svl)/(d1+0.5f);
  float t1 = (sav+sal)/(d2+0.5f);
  float t2 = (sal+svl)/(d3+0.5f);
  float t3 = (sav+sl)/(d4+0.5f);
  float t4 = (sal+sv)/(d5+0.5f);
  float t5 = (sa+svl)/(d6+0.5f);
  float mx = fmaxf(fmaxf(fmaxf(t0,t1),fmaxf(t2,t3)),fmaxf(t4,t5));
  float g0=__expf(t0-mx),g1=__expf(t1-mx),g2=__expf(t2-mx);
  float g3=__expf(t3-mx),g4=__expf(t4-mx),g5=__expf(t5-mx);
  float gs = g0+g1+g2+g3+g4+g5;
  if(lane == 0){
    float wt[6] = {g0/gs,g1/gs,g2/gs,g3/gs,g4/gs,g5/gs};
    float* twr = tw + (size_t)r*12;
    #pragma unroll
    for(int p = 0; p < 6; p++){ st[15+p] = wt[p]; twr[6+p] = wt[p]; }
  }
}

// ---------- K6 precompute: WpT (64 x 5120 bf16), BN folded ----------
__global__ __launch_bounds__(256) void k6_prew(
    const float* __restrict__ gamma, const float* __restrict__ l1W,
    u16* __restrict__ WpT)
{
  int kk = blockIdx.x * 256 + threadIdx.x;   // 0..5119 (grid.x = 20)
  int j  = blockIdx.y;                        // 0..63
  const float gsc = 1.0f / sqrtf(1.0f + 1e-5f);
  int korig; float sc;
  if(kk < 1024){ korig = kk; sc = 1.f; }
  else if(kk < 4096){ korig = 1024 + ((kk - 1024) & 1023); sc = 1.0f/3.0f; }
  else { korig = 2048 + (kk - 4096); sc = 1.f; }
  float v = (j < 50) ? l1W[(size_t)korig*50 + j] * gamma[korig] * gsc * sc : 0.f;
  WpT[(size_t)j*KF + kk] = f2bf(v);
}

// ---------- K6 precompute: bp[j] = l1b[j] + beta @ l1W ----------
__global__ __launch_bounds__(256) void k6_preb(
    const float* __restrict__ beta, const float* __restrict__ l1W,
    const float* __restrict__ l1b, float* __restrict__ bp)
{
  __shared__ float red[4][64];
  int j = threadIdx.x & 63, seg = threadIdx.x >> 6;
  float s = 0.f;
  if(j < 50){
    for(int k = seg*768; k < seg*768 + 768; k++)
      s = fmaf(beta[k], l1W[(size_t)k*50 + j], s);
  }
  red[seg][j] = s;
  __syncthreads();
  if(seg == 0){
    float t = red[0][j] + red[1][j] + red[2][j] + red[3][j];
    bp[j] = (j < 50) ? (l1b[j] + t) : 0.f;
  }
}

// ---------- K6: MFMA GEMM (NB x 5120)@(5120 x 64) + MLP tail + softmax ----------
// M-tile 16, 4 waves split K (1280 each), LDS partial reduction.
__global__ __launch_bounds__(256) void k6_mfma(
    const u16* __restrict__ Fcat, const u16* __restrict__ WpT,
    const float* __restrict__ bp,
    const float* __restrict__ l2W, const float* __restrict__ l2b,
    const float* __restrict__ l3W, const float* __restrict__ l3b,
    float* __restrict__ y2out)
{
  __shared__ float Part[4][16][64];
  __shared__ float Ys[16][52];
  __shared__ float W2s[50][64];
  __shared__ float W3s[50][8];
  __shared__ float Ys2[16][52];

  int tid = threadIdx.x;
  int wv = tid >> 6, lane = tid & 63;
  int fr = lane & 15, kg = lane >> 4;
  int rb = blockIdx.x * 16;

  for(int t = tid; t < 50*64; t += 256){
    int k = t >> 6, c = t & 63;
    W2s[k][c] = (c < 50) ? l2W[k*50 + c] : 0.f;
  }
  for(int t = tid; t < 400; t += 256)
    W3s[t/8][t%8] = l3W[t];

  const u16* aptr = Fcat + (size_t)(rb + fr)*KF + wv*1280 + kg*8;
  const u16* bptr = WpT  + (size_t)fr*KF       + wv*1280 + kg*8;

  f32x4 zero = {0.f,0.f,0.f,0.f};
  f32x4 acc[4];
  #pragma unroll
  for(int cf = 0; cf < 4; cf++) acc[cf] = zero;

  for(int k0 = 0; k0 < 1280; k0 += 64){
    bf16x8 a0 = *(const bf16x8*)(aptr + k0);
    bf16x8 a1 = *(const bf16x8*)(aptr + k0 + 32);
    #pragma unroll
    for(int cf = 0; cf < 4; cf++){
      bf16x8 b0 = *(const bf16x8*)(bptr + (size_t)cf*16*KF + k0);
      bf16x8 b1 = *(const bf16x8*)(bptr + (size_t)cf*16*KF + k0 + 32);
      acc[cf] = __builtin_amdgcn_mfma_f32_16x16x32_bf16(a0, b0, acc[cf], 0, 0, 0);
      acc[cf] = __builtin_amdgcn_mfma_f32_16x16x32_bf16(a1, b1, acc[cf], 0, 0, 0);
    }
  }
  #pragma unroll
  for(int cf = 0; cf < 4; cf++)
    #pragma unroll
    for(int q = 0; q < 4; q++)
      Part[wv][kg*4 + q][cf*16 + fr] = acc[cf][q];
  __syncthreads();

  // reduce K-partials + bias + tanh
  for(int t = tid; t < 1024; t += 256){
    int r = t >> 6, c = t & 63;
    float z = Part[0][r][c] + Part[1][r][c] + Part[2][r][c] + Part[3][r][c] + bp[c];
    if(c < 50) Ys[r][c] = fast_tanh(z);
  }
  __syncthreads();

  // stage 2: 16 rows x 16 threads, 4 cols each
  {
    int r = tid >> 4, q = tid & 15;
    float a2[4] = {0,0,0,0};
    for(int k = 0; k < 50; k++){
      float yv = Ys[r][k];
      #pragma unroll
      for(int c = 0; c < 4; c++) a2[c] = fmaf(yv, W2s[k][q*4 + c], a2[c]);
    }
    #pragma unroll
    for(int c = 0; c < 4; c++){
      int cc = q*4 + c;
      if(cc < 50) Ys2[r][cc] = fast_tanh(a2[c] + l2b[cc]);
    }
  }
  __syncthreads();

  // stage 3: 128 threads: r = tid>>3, c = tid&7, softmax over 8
  if(tid < 128){
    int r = tid >> 3, c = tid & 7;
    float z = l3b[c];
    for(int k = 0; k < 50; k++) z = fmaf(Ys2[r][k], W3s[k][c], z);
    float m = z;
    m = fmaxf(m, __shfl_xor(m, 1));
    m = fmaxf(m, __shfl_xor(m, 2));
    m = fmaxf(m, __shfl_xor(m, 4));
    float e = __expf(z - m);
    float s = e;
    s += __shfl_xor(s, 1); s += __shfl_xor(s, 2); s += __shfl_xor(s, 4);
    y2out[(size_t)(rb + r)*8 + c] = e / s;
  }
}

// ---------- launch ----------
extern "C" void kernel_launch(void* const* d_in, const int* in_sizes, int n_in,
                              void* d_out, int out_size, void* d_ws, size_t ws_size,
                              hipStream_t stream)
{
  (void)in_sizes; (void)n_in; (void)out_size; (void)ws_size;
  const float* x    = (const float*)d_in[0];
  const float* attW = (const float*)d_in[1];
  const float* attb = (const float*)d_in[2];
  const float* gfW1 = (const float*)d_in[3];
  const float* gfb1 = (const float*)d_in[4];
  const float* gfW2 = (const float*)d_in[5];
  const float* gfb2 = (const float*)d_in[6];
  const float* bng  = (const float*)d_in[7];
  const float* bnb  = (const float*)d_in[8];
  const float* l1W  = (const float*)d_in[9];
  const float* l1b  = (const float*)d_in[10];
  const float* l2W  = (const float*)d_in[11];
  const float* l2b  = (const float*)d_in[12];
  const float* l3W  = (const float*)d_in[13];
  const float* l3b  = (const float*)d_in[14];

  float* out = (float*)d_out;
  float* tw  = out + (size_t)NB*8;

  // workspace layout (~233 MB)
  float* ws    = (float*)d_ws;
  float* stats = ws;                               // NB*24 f32
  float* UV1   = stats + (size_t)NB*24;            // 3*NB*128 f32
  float* UV2   = UV1 + (size_t)3*NB*128;           // 3*NB*128 f32
  float* bp    = UV2 + (size_t)3*NB*128;           // 64 f32
  u16* WpT     = (u16*)(bp + 64);                  // 64*KF bf16
  u16* Wb1     = WpT + (size_t)64*KF;              // 128*1024 bf16
  u16* W2T     = Wb1 + (size_t)128*1024;           // 1024*64 bf16
  u16* T       = W2T + (size_t)1024*64;            // 6*NB*64 bf16 (bi aliases tri)
  u16* Fcat    = T + (size_t)6*NB*64;              // NB*KF bf16

  k1_stats<<<dim3(NB/4), dim3(256), 0, stream>>>(x, attW, attb, stats, Fcat, tw);
  kprew_b1<<<dim3(512), dim3(256), 0, stream>>>(gfW1, Wb1);
  kprew_w2t<<<dim3(256), dim3(256), 0, stream>>>(gfW2, W2T);
  k6_prew<<<dim3(20, 64), dim3(256), 0, stream>>>(bng, l1W, WpT);
  k6_preb<<<dim3(1), dim3(256), 0, stream>>>(bnb, l1W, l1b, bp);

  kg1_mfma<1><<<dim3(3*NB/64), dim3(256), 0, stream>>>(x, (const u16*)nullptr, Wb1, UV1);
  kT_bi<<<dim3(3*NB*8/256), dim3(256), 0, stream>>>(UV1, gfb1, T);
  kL2_mfma<3,0><<<dim3(NB/16, 4), dim3(256), 0, stream>>>(T, W2T, gfb2, stats, Fcat);
  k3s_stats2<<<dim3(NB/4), dim3(256), 0, stream>>>(Fcat, x, stats, tw);
  kg1_mfma<0><<<dim3(3*NB/64), dim3(256), 0, stream>>>((const float*)nullptr, Fcat, Wb1, UV2);
  kT_tri<<<dim3(6*NB*8/256), dim3(256), 0, stream>>>(UV2, UV1, gfb1, T);
  kL2_mfma<6,1><<<dim3(NB/16, 4), dim3(256), 0, stream>>>(T, W2T, gfb2, stats, Fcat);
  k6_mfma<<<dim3(NB/16), dim3(256), 0, stream>>>(Fcat, WpT, bp, l2W, l2b, l3W, l3b, out);
}

// Round 4
// 562.153 us; speedup vs baseline: 2.6667x; 1.1885x over previous
//
#include <hip/hip_runtime.h>
#include <math.h>

#define NB 16384
#define DD 1024
#define KF 5120   // concat feature K: uni(1024) + a_v,a_l,v_l(3*1024) + tri(1024)

typedef unsigned short u16;
typedef unsigned int u32;
typedef __attribute__((ext_vector_type(8))) short bf16x8;
typedef __attribute__((ext_vector_type(4))) float f32x4;

// ---------- helpers ----------
__device__ __forceinline__ float bf2f(u16 u){
  return __uint_as_float(((unsigned)u) << 16);
}
__device__ __forceinline__ u16 f2bf(float f){
  unsigned u = __float_as_uint(f);
  return (u16)((u + 0x7fffu + ((u >> 16) & 1u)) >> 16);   // RNE
}
__device__ __forceinline__ float fast_tanh(float x){
  float e = __expf(2.0f * x);
  return 1.0f - 2.0f / (e + 1.0f);
}
__device__ __forceinline__ float wredsum(float x){
  #pragma unroll
  for(int o = 32; o >= 1; o >>= 1) x += __shfl_xor(x, o);
  return x;
}
__device__ __forceinline__ float wredmax(float x){
  #pragma unroll
  for(int o = 32; o >= 1; o >>= 1) x = fmaxf(x, __shfl_xor(x, o));
  return x;
}
__device__ __forceinline__ bf16x8 pack8f(float4 f0, float4 f1){
  bf16x8 r;
  r[0]=(short)f2bf(f0.x); r[1]=(short)f2bf(f0.y); r[2]=(short)f2bf(f0.z); r[3]=(short)f2bf(f0.w);
  r[4]=(short)f2bf(f1.x); r[5]=(short)f2bf(f1.y); r[6]=(short)f2bf(f1.z); r[7]=(short)f2bf(f1.w);
  return r;
}
// async global->LDS, 16B per lane; LDS dest = uniform base + lane*16
__device__ __forceinline__ void gll16(const void* g, void* l){
  __builtin_amdgcn_global_load_lds(
      (const __attribute__((address_space(1))) u32*)g,
      (__attribute__((address_space(3))) u32*)l, 16, 0, 0);
}

// ---------- K1: per-row stats, w_uni, w_bi, unimodal ----------
__global__ __launch_bounds__(256) void k1_stats(
    const float* __restrict__ x, const float* __restrict__ attW,
    const float* __restrict__ attb, float* __restrict__ stats,
    u16* __restrict__ Fcat, float* __restrict__ tw)
{
  int wave = threadIdx.x >> 6, lane = threadIdx.x & 63;
  int r = blockIdx.x * 4 + wave;
  const float* xr = x + (size_t)r * 3 * DD;
  float a[16], v[16], l[16];
  float dA=0.f,dV=0.f,dL=0.f, mA=-1e30f,mV=-1e30f,mL=-1e30f;
  #pragma unroll
  for(int i = 0; i < 16; i++){
    int k = lane + i*64;
    a[i] = xr[k]; v[i] = xr[DD+k]; l[i] = xr[2*DD+k];
    float w = attW[k];
    dA = fmaf(a[i], w, dA); dV = fmaf(v[i], w, dV); dL = fmaf(l[i], w, dL);
    mA = fmaxf(mA, a[i]); mV = fmaxf(mV, v[i]); mL = fmaxf(mL, l[i]);
  }
  dA = wredsum(dA); dV = wredsum(dV); dL = wredsum(dL);
  mA = wredmax(mA); mV = wredmax(mV); mL = wredmax(mL);

  float Sa=0.f,Sv=0.f,Sl=0.f,Eav=0.f,Eal=0.f,Evl=0.f;
  #pragma unroll
  for(int i = 0; i < 16; i++){
    float ea = __expf(a[i]-mA), ev = __expf(v[i]-mV), el = __expf(l[i]-mL);
    Sa += ea; Sv += ev; Sl += el;
    Eav += ea*ev; Eal += ea*el; Evl += ev*el;
  }
  Sa = wredsum(Sa); Sv = wredsum(Sv); Sl = wredsum(Sl);
  Eav = wredsum(Eav); Eal = wredsum(Eal); Evl = wredsum(Evl);

  float ab = attb[0];
  float ta = fast_tanh(dA + ab), tv = fast_tanh(dV + ab), tl = fast_tanh(dL + ab);
  float mm = fmaxf(ta, fmaxf(tv, tl));
  float e0 = __expf(ta-mm), e1 = __expf(tv-mm), e2 = __expf(tl-mm);
  float ss = e0 + e1 + e2;
  float sa = e0/ss, sv = e1/ss, sl = e2/ss;
  float dav = Eav/(Sa*Sv), dal = Eal/(Sa*Sl), dvl = Evl/(Sv*Sl);
  float sav = (sa+sv)/(dav+0.5f);
  float sal = (sa+sl)/(dal+0.5f);
  float svl = (sv+sl)/(dvl+0.5f);
  float m2 = fmaxf(sav, fmaxf(sal, svl));
  float f0 = __expf(sav-m2), f1 = __expf(sal-m2), f2 = __expf(svl-m2);
  float s2 = f0 + f1 + f2;
  float wb0 = f0/s2, wb1 = f1/s2, wb2 = f2/s2;

  if(lane == 0){
    float* st = stats + (size_t)r*24;
    st[0]=sa; st[1]=sv; st[2]=sl;
    st[3]=wb0; st[4]=wb1; st[5]=wb2;
    st[6]=sav; st[7]=sal; st[8]=svl;
    st[9]=mA; st[10]=Sa; st[11]=mV; st[12]=Sv; st[13]=mL; st[14]=Sl;
    float* twr = tw + (size_t)r*12;
    twr[0]=sa; twr[1]=sv; twr[2]=sl; twr[3]=wb0; twr[4]=wb1; twr[5]=wb2;
  }
  #pragma unroll
  for(int i = 0; i < 16; i++){
    int k = lane + i*64;
    Fcat[(size_t)r*KF + k] = f2bf((sa*a[i] + sv*v[i] + sl*l[i]) * (1.0f/3.0f));
  }
}

// ---------- precompute: Wb1 (128 x 1024 bf16): [n][k], n<64 -> U cols, else V ----------
__global__ __launch_bounds__(256) void kprew_b1(
    const float* __restrict__ W1, u16* __restrict__ Wb1)
{
  int idx = blockIdx.x * 256 + threadIdx.x;   // 0..131071
  int n = idx >> 10, k = idx & 1023;
  float v = (n < 64) ? W1[(size_t)k*64 + n] : W1[(size_t)(1024+k)*64 + (n-64)];
  Wb1[idx] = f2bf(v);
}

// ---------- precompute: W2T (1024 x 64 bf16): [c][k] = W2[k][c] ----------
__global__ __launch_bounds__(256) void kprew_w2t(
    const float* __restrict__ W2, u16* __restrict__ W2T)
{
  int idx = blockIdx.x * 256 + threadIdx.x;   // 0..65535
  int c = idx >> 6, k = idx & 63;
  W2T[idx] = f2bf(W2[(size_t)k*DD + c]);
}

// ---------- layer-1 MFMA GEMM v2: (3NB,1024) @ Wb1^T -> UV (3NB x 128 fp32) ----------
// block: 256 thr / 4 waves; M-tile 64, N=128; waves split N (32 cols each).
// A staged in LDS, double-buffered, XOR-swizzled; B streamed from L2.
template<int FROM_X>
__global__ __launch_bounds__(256) void kg1v2(
    const float* __restrict__ xf, const u16* __restrict__ fc,
    const u16* __restrict__ Wb1, float* __restrict__ UV)
{
  __shared__ u16 Asm[2][64*64];   // 2 x 8KB
  int tid = threadIdx.x;
  int wv = tid >> 6, lane = tid & 63;
  int fr = lane & 15, kg = lane >> 4;
  int mb = blockIdx.x * 64;

  // gll sources (FROM_X==0): wave issues instrs g=2wv, 2wv+1 (rows 8g..8g+7)
  const u16* gsrc0 = nullptr; const u16* gsrc1 = nullptr;
  // reg-stage source (FROM_X==1): thread covers rows rr_ and rr_+32, k-part pp_
  const float* xsrc0 = nullptr; const float* xsrc1 = nullptr;
  int rr_ = tid >> 3, pp_ = tid & 7;
  int sp_ = pp_ ^ (rr_ & 7);
  if(FROM_X){
    xsrc0 = xf + (size_t)(mb + rr_)*1024 + pp_*8;
    xsrc1 = xf + (size_t)(mb + rr_ + 32)*1024 + pp_*8;
  } else {
    int r8 = lane >> 3, p = lane & 7;
    int sp = p ^ (r8 & 7);
    int m0 = mb + (2*wv)*8 + r8;
    int m1 = mb + (2*wv+1)*8 + r8;
    int R0 = m0/3, R1 = m1/3;
    gsrc0 = fc + (size_t)R0*KF + (size_t)(1 + (m0 - 3*R0))*1024 + sp*8;
    gsrc1 = fc + (size_t)R1*KF + (size_t)(1 + (m1 - 3*R1))*1024 + sp*8;
  }

  f32x4 acc[4][2];
  #pragma unroll
  for(int rf = 0; rf < 4; rf++)
    #pragma unroll
    for(int nf = 0; nf < 2; nf++) acc[rf][nf] = (f32x4){0.f,0.f,0.f,0.f};

  // prologue: stage chunk 0 into buf 0
  if(FROM_X){
    float4 a0 = *(const float4*)xsrc0, a1 = *(const float4*)(xsrc0+4);
    float4 c0 = *(const float4*)xsrc1, c1 = *(const float4*)(xsrc1+4);
    *(bf16x8*)&Asm[0][rr_*64 + sp_*8]      = pack8f(a0,a1);
    *(bf16x8*)&Asm[0][(rr_+32)*64 + sp_*8] = pack8f(c0,c1);
  } else {
    gll16(gsrc0, &Asm[0][(2*wv)*512]);
    gll16(gsrc1, &Asm[0][(2*wv+1)*512]);
  }
  __syncthreads();

  int buf = 0;
  for(int ci = 0; ci < 16; ci++){
    int k0 = ci*64;
    float4 na0, na1, nc0, nc1;
    if(ci < 15){
      if(FROM_X){
        na0 = *(const float4*)(xsrc0 + k0 + 64); na1 = *(const float4*)(xsrc0 + k0 + 68);
        nc0 = *(const float4*)(xsrc1 + k0 + 64); nc1 = *(const float4*)(xsrc1 + k0 + 68);
      } else {
        gll16(gsrc0 + k0 + 64, &Asm[buf^1][(2*wv)*512]);
        gll16(gsrc1 + k0 + 64, &Asm[buf^1][(2*wv+1)*512]);
      }
    }
    #pragma unroll
    for(int ks = 0; ks < 2; ks++){
      bf16x8 a[4];
      #pragma unroll
      for(int rf = 0; rf < 4; rf++){
        int row = rf*16 + fr;
        int slot = (ks*4 + kg) ^ (fr & 7);
        a[rf] = *(const bf16x8*)&Asm[buf][row*64 + slot*8];
      }
      #pragma unroll
      for(int nf = 0; nf < 2; nf++){
        int col = wv*32 + nf*16 + fr;
        bf16x8 b = *(const bf16x8*)&Wb1[(size_t)col*1024 + k0 + ks*32 + kg*8];
        #pragma unroll
        for(int rf = 0; rf < 4; rf++)
          acc[rf][nf] = __builtin_amdgcn_mfma_f32_16x16x32_bf16(a[rf], b, acc[rf][nf], 0, 0, 0);
      }
    }
    if(FROM_X && ci < 15){
      *(bf16x8*)&Asm[buf^1][rr_*64 + sp_*8]      = pack8f(na0,na1);
      *(bf16x8*)&Asm[buf^1][(rr_+32)*64 + sp_*8] = pack8f(nc0,nc1);
    }
    __syncthreads();
    buf ^= 1;
  }

  #pragma unroll
  for(int rf = 0; rf < 4; rf++)
    #pragma unroll
    for(int nf = 0; nf < 2; nf++)
      #pragma unroll
      for(int q = 0; q < 4; q++)
        UV[(size_t)(mb + rf*16 + kg*4 + q)*128 + wv*32 + nf*16 + fr] = acc[rf][nf][q];
}

// ---------- layer-2 MFMA: t = lrelu(U+V+b1) built in-register from UV ----------
// block: 16 rows x 256 cols, 4 waves (64 cols each), P pairs in-register.
template<int P, int SUM>
__global__ __launch_bounds__(256) void kL2_mfma(
    const float* __restrict__ UVA, const float* __restrict__ UVB,
    const u16* __restrict__ W2T, const float* __restrict__ b1,
    const float* __restrict__ b2, const float* __restrict__ stats,
    u16* __restrict__ Fcat)
{
  int tid = threadIdx.x;
  int wv = tid >> 6, lane = tid & 63;
  int fr = lane & 15, kg = lane >> 4;
  int Rb = blockIdx.x * 16;
  int cb = blockIdx.y * 256 + wv * 64;
  int R = Rb + fr;

  f32x4 acc[P][4];
  #pragma unroll
  for(int p = 0; p < P; p++)
    #pragma unroll
    for(int cf = 0; cf < 4; cf++) acc[p][cf] = (f32x4){0.f,0.f,0.f,0.f};

  #pragma unroll
  for(int ks = 0; ks < 2; ks++){
    int j0 = ks*32 + kg*8;
    float4 bb0 = *(const float4*)(b1 + j0), bb1 = *(const float4*)(b1 + j0 + 4);
    bf16x8 a[P];
    #pragma unroll
    for(int p = 0; p < P; p++){
      int up, vp;
      const float* VB;
      if(P == 3){
        up = (p == 2) ? 1 : 0;           // a1,a1,v1
        vp = (p == 0) ? 1 : 2;           // v1,l1,l1
        VB = UVA;
      } else {
        up = (0x210200 >> (p*4)) & 15;   // a_v,a_v,v_l,a_v,a_l,v_l
        vp = (0x012112 >> (p*4)) & 15;   // v_l,a_l,a_l,l1,v1,a1
        VB = (p < 3) ? UVA : UVB;
      }
      const float* Up = UVA + (size_t)(3*R + up)*128 + j0;
      const float* Vp = VB  + (size_t)(3*R + vp)*128 + 64 + j0;
      float4 u0 = *(const float4*)Up, u1 = *(const float4*)(Up+4);
      float4 v0 = *(const float4*)Vp, v1 = *(const float4*)(Vp+4);
      float t[8] = {u0.x+v0.x+bb0.x, u0.y+v0.y+bb0.y, u0.z+v0.z+bb0.z, u0.w+v0.w+bb0.w,
                    u1.x+v1.x+bb1.x, u1.y+v1.y+bb1.y, u1.z+v1.z+bb1.z, u1.w+v1.w+bb1.w};
      bf16x8 o;
      #pragma unroll
      for(int j = 0; j < 8; j++){
        float tv = t[j] > 0.f ? t[j] : 0.2f*t[j];
        o[j] = (short)f2bf(tv);
      }
      a[p] = o;
    }
    #pragma unroll
    for(int cf = 0; cf < 4; cf++){
      bf16x8 b = *(const bf16x8*)&W2T[(size_t)(cb + cf*16 + fr)*64 + j0];
      #pragma unroll
      for(int p = 0; p < P; p++)
        acc[p][cf] = __builtin_amdgcn_mfma_f32_16x16x32_bf16(a[p], b, acc[p][cf], 0, 0, 0);
    }
  }

  #pragma unroll
  for(int q = 0; q < 4; q++){
    int Rq = Rb + kg*4 + q;
    const float* st = stats + (size_t)Rq*24;
    #pragma unroll
    for(int cf = 0; cf < 4; cf++){
      int c = cb + cf*16 + fr;
      float b2c = b2[c];
      if(SUM){
        float s = 0.f;
        #pragma unroll
        for(int p = 0; p < P; p++){
          float g = st[15+p] * fast_tanh(acc[p][cf][q] + b2c);
          s += g > 0.f ? g : 0.01f*g;
        }
        Fcat[(size_t)Rq*KF + 4096 + c] = f2bf(s * (1.0f/6.0f));
      } else {
        #pragma unroll
        for(int p = 0; p < P; p++){
          float g = st[3+p] * fast_tanh(acc[p][cf][q] + b2c);
          float val = g > 0.f ? g : 0.01f*g;
          Fcat[(size_t)Rq*KF + (size_t)(1+p)*1024 + c] = f2bf(val);
        }
      }
    }
  }
}

// ---------- K3s: softmax stats of a_v/a_l/v_l + cross dots -> w_tri ----------
__global__ __launch_bounds__(256) void k3s_stats2(
    const u16* __restrict__ Fcat, const float* __restrict__ x,
    float* __restrict__ stats, float* __restrict__ tw)
{
  int wave = threadIdx.x >> 6, lane = threadIdx.x & 63;
  int r = blockIdx.x * 4 + wave;
  const u16*   pv = Fcat + (size_t)r*KF + 1024;
  const float* xr = x    + (size_t)3*r*DD;
  float av[16], al[16], vl[16];
  float mav=-1e30f, mal=-1e30f, mvl=-1e30f;
  #pragma unroll
  for(int i = 0; i < 16; i++){
    int k = lane + i*64;
    av[i] = bf2f(pv[k]); al[i] = bf2f(pv[DD+k]); vl[i] = bf2f(pv[2*DD+k]);
    mav = fmaxf(mav, av[i]); mal = fmaxf(mal, al[i]); mvl = fmaxf(mvl, vl[i]);
  }
  mav = wredmax(mav); mal = wredmax(mal); mvl = wredmax(mvl);

  float* st = stats + (size_t)r*24;
  float sa=st[0], sv=st[1], sl=st[2];
  float sav=st[6], sal=st[7], svl=st[8];
  float mA=st[9], Sa=st[10], mV=st[11], Sv=st[12], mL=st[13], Sl=st[14];

  float Savv=0.f,Sall=0.f,Svll=0.f,E1=0.f,E2=0.f,E3=0.f,E4=0.f,E5=0.f,E6=0.f;
  #pragma unroll
  for(int i = 0; i < 16; i++){
    int k = lane + i*64;
    float a1 = xr[k], v1 = xr[DD+k], l1 = xr[2*DD+k];
    float eav = __expf(av[i]-mav), eal = __expf(al[i]-mal), evl = __expf(vl[i]-mvl);
    Savv += eav; Sall += eal; Svll += evl;
    float ea = __expf(a1-mA), ev = __expf(v1-mV), el = __expf(l1-mL);
    E1 += eav*evl; E2 += eav*eal; E3 += eal*evl;
    E4 += eav*el;  E5 += eal*ev;  E6 += evl*ea;
  }
  Savv = wredsum(Savv); Sall = wredsum(Sall); Svll = wredsum(Svll);
  E1 = wredsum(E1); E2 = wredsum(E2); E3 = wredsum(E3);
  E4 = wredsum(E4); E5 = wredsum(E5); E6 = wredsum(E6);

  float d1 = E1/(Savv*Svll), d2 = E2/(Savv*Sall), d3 = E3/(Sall*Svll);
  float d4 = E4/(Savv*Sl),   d5 = E5/(Sall*Sv),   d6 = E6/(Svll*Sa);
  float t0 = (sav+svl)/(d1+0.5f);
  float t1 = (sav+sal)/(d2+0.5f);
  float t2 = (sal+svl)/(d3+0.5f);
  float t3 = (sav+sl)/(d4+0.5f);
  float t4 = (sal+sv)/(d5+0.5f);
  float t5 = (sa+svl)/(d6+0.5f);
  float mx = fmaxf(fmaxf(fmaxf(t0,t1),fmaxf(t2,t3)),fmaxf(t4,t5));
  float g0=__expf(t0-mx),g1=__expf(t1-mx),g2=__expf(t2-mx);
  float g3=__expf(t3-mx),g4=__expf(t4-mx),g5=__expf(t5-mx);
  float gs = g0+g1+g2+g3+g4+g5;
  if(lane == 0){
    float wt[6] = {g0/gs,g1/gs,g2/gs,g3/gs,g4/gs,g5/gs};
    float* twr = tw + (size_t)r*12;
    #pragma unroll
    for(int p = 0; p < 6; p++){ st[15+p] = wt[p]; twr[6+p] = wt[p]; }
  }
}

// ---------- K6 precompute: WpT (64 x 5120 bf16), BN folded ----------
__global__ __launch_bounds__(256) void k6_prew(
    const float* __restrict__ gamma, const float* __restrict__ l1W,
    u16* __restrict__ WpT)
{
  int kk = blockIdx.x * 256 + threadIdx.x;   // 0..5119 (grid.x = 20)
  int j  = blockIdx.y;                        // 0..63
  const float gsc = 1.0f / sqrtf(1.0f + 1e-5f);
  int korig; float sc;
  if(kk < 1024){ korig = kk; sc = 1.f; }
  else if(kk < 4096){ korig = 1024 + ((kk - 1024) & 1023); sc = 1.0f/3.0f; }
  else { korig = 2048 + (kk - 4096); sc = 1.f; }
  float v = (j < 50) ? l1W[(size_t)korig*50 + j] * gamma[korig] * gsc * sc : 0.f;
  WpT[(size_t)j*KF + kk] = f2bf(v);
}

// ---------- K6 precompute: bp[j] = l1b[j] + beta @ l1W ----------
__global__ __launch_bounds__(256) void k6_preb(
    const float* __restrict__ beta, const float* __restrict__ l1W,
    const float* __restrict__ l1b, float* __restrict__ bp)
{
  __shared__ float red[4][64];
  int j = threadIdx.x & 63, seg = threadIdx.x >> 6;
  float s = 0.f;
  if(j < 50){
    for(int k = seg*768; k < seg*768 + 768; k++)
      s = fmaf(beta[k], l1W[(size_t)k*50 + j], s);
  }
  red[seg][j] = s;
  __syncthreads();
  if(seg == 0){
    float t = red[0][j] + red[1][j] + red[2][j] + red[3][j];
    bp[j] = (j < 50) ? (l1b[j] + t) : 0.f;
  }
}

// ---------- K6 v2: (NB x 5120)@(5120 x 64) + MLP tail; 1024 thr, 16 waves ----------
// waves = 4 K-quarters x 4 col-frags; A LDS-staged dbuf; Part reduce; fused tail.
__global__ __launch_bounds__(1024) void k6v2(
    const u16* __restrict__ Fcat, const u16* __restrict__ WpT,
    const float* __restrict__ bp,
    const float* __restrict__ l2W, const float* __restrict__ l2b,
    const float* __restrict__ l3W, const float* __restrict__ l3b,
    float* __restrict__ y2out)
{
  __shared__ u16  Asm[4][2][64*64];    // 64 KB: per-kq double-buffered A chunks
  __shared__ float Part[4][64][64];    // 64 KB
  float* Ys  = (float*)&Asm[0][0][0];  // tail aliases Asm: [64][56]
  float* Ys2 = Ys  + 64*56;
  float* W2s = Ys2 + 64*56;            // [50][64]
  float* W3s = W2s + 50*64;            // [50][8]

  int tid = threadIdx.x;
  int w = tid >> 6, lane = tid & 63;
  int kq = w & 3, cf = w >> 2;
  int fr = lane & 15, kg = lane >> 4;
  int rb = blockIdx.x * 64;
  int koff = kq * 1280;

  int r8 = lane >> 3, p = lane & 7;
  int sp = p ^ (r8 & 7);
  const u16* gsrc0 = Fcat + (size_t)(rb + (2*cf)*8   + r8)*KF + koff + sp*8;
  const u16* gsrc1 = Fcat + (size_t)(rb + (2*cf+1)*8 + r8)*KF + koff + sp*8;
  const u16* bptr  = WpT + (size_t)(cf*16 + fr)*KF + koff + kg*8;

  f32x4 acc[4];
  #pragma unroll
  for(int rf = 0; rf < 4; rf++) acc[rf] = (f32x4){0.f,0.f,0.f,0.f};

  gll16(gsrc0, &Asm[kq][0][(2*cf)*512]);
  gll16(gsrc1, &Asm[kq][0][(2*cf+1)*512]);
  __syncthreads();

  int buf = 0;
  for(int ci = 0; ci < 20; ci++){
    int k0 = ci*64;
    if(ci < 19){
      gll16(gsrc0 + k0 + 64, &Asm[kq][buf^1][(2*cf)*512]);
      gll16(gsrc1 + k0 + 64, &Asm[kq][buf^1][(2*cf+1)*512]);
    }
    #pragma unroll
    for(int ks = 0; ks < 2; ks++){
      bf16x8 b = *(const bf16x8*)(bptr + k0 + ks*32);
      #pragma unroll
      for(int rf = 0; rf < 4; rf++){
        int row = rf*16 + fr;
        int slot = (ks*4 + kg) ^ (fr & 7);
        bf16x8 a = *(const bf16x8*)&Asm[kq][buf][row*64 + slot*8];
        acc[rf] = __builtin_amdgcn_mfma_f32_16x16x32_bf16(a, b, acc[rf], 0, 0, 0);
      }
    }
    __syncthreads();
    buf ^= 1;
  }

  #pragma unroll
  for(int rf = 0; rf < 4; rf++)
    #pragma unroll
    for(int q = 0; q < 4; q++)
      Part[kq][rf*16 + kg*4 + q][cf*16 + fr] = acc[rf][q];
  __syncthreads();

  // reduce K-partials + bias + tanh -> Ys (aliases Asm; Part untouched)
  {
    int r = tid >> 4, c4 = (tid & 15) * 4;
    float4 p0 = *(const float4*)&Part[0][r][c4];
    float4 p1 = *(const float4*)&Part[1][r][c4];
    float4 p2 = *(const float4*)&Part[2][r][c4];
    float4 p3 = *(const float4*)&Part[3][r][c4];
    float z[4] = {p0.x+p1.x+p2.x+p3.x, p0.y+p1.y+p2.y+p3.y,
                  p0.z+p1.z+p2.z+p3.z, p0.w+p1.w+p2.w+p3.w};
    #pragma unroll
    for(int j = 0; j < 4; j++){
      int c = c4 + j;
      if(c < 50) Ys[r*56 + c] = fast_tanh(z[j] + bp[c]);
    }
  }
  for(int t = tid; t < 3200; t += 1024){
    int k = t >> 6, c = t & 63;
    W2s[t] = (c < 50) ? l2W[k*50 + c] : 0.f;
  }
  for(int t = tid; t < 400; t += 1024) W3s[t] = l3W[t];
  __syncthreads();

  // stage 2: Ys(64x50) @ W2 -> tanh -> Ys2
  {
    int r = tid >> 4, q = tid & 15;
    float a2[4] = {0,0,0,0};
    for(int k = 0; k < 50; k++){
      float yv = Ys[r*56 + k];
      #pragma unroll
      for(int c = 0; c < 4; c++) a2[c] = fmaf(yv, W2s[k*64 + q*4 + c], a2[c]);
    }
    #pragma unroll
    for(int c = 0; c < 4; c++){
      int cc = q*4 + c;
      if(cc < 50) Ys2[r*56 + cc] = fast_tanh(a2[c] + l2b[cc]);
    }
  }
  __syncthreads();

  // stage 3: Ys2(64x50) @ W3 + b3, softmax over 8
  if(tid < 512){
    int r = tid >> 3, c = tid & 7;
    float z = l3b[c];
    for(int k = 0; k < 50; k++) z = fmaf(Ys2[r*56 + k], W3s[k*8 + c], z);
    float m = z;
    m = fmaxf(m, __shfl_xor(m, 1));
    m = fmaxf(m, __shfl_xor(m, 2));
    m = fmaxf(m, __shfl_xor(m, 4));
    float e = __expf(z - m);
    float s = e;
    s += __shfl_xor(s, 1); s += __shfl_xor(s, 2); s += __shfl_xor(s, 4);
    y2out[(size_t)(rb + r)*8 + c] = e / s;
  }
}

// ---------- launch ----------
extern "C" void kernel_launch(void* const* d_in, const int* in_sizes, int n_in,
                              void* d_out, int out_size, void* d_ws, size_t ws_size,
                              hipStream_t stream)
{
  (void)in_sizes; (void)n_in; (void)out_size; (void)ws_size;
  const float* x    = (const float*)d_in[0];
  const float* attW = (const float*)d_in[1];
  const float* attb = (const float*)d_in[2];
  const float* gfW1 = (const float*)d_in[3];
  const float* gfb1 = (const float*)d_in[4];
  const float* gfW2 = (const float*)d_in[5];
  const float* gfb2 = (const float*)d_in[6];
  const float* bng  = (const float*)d_in[7];
  const float* bnb  = (const float*)d_in[8];
  const float* l1W  = (const float*)d_in[9];
  const float* l1b  = (const float*)d_in[10];
  const float* l2W  = (const float*)d_in[11];
  const float* l2b  = (const float*)d_in[12];
  const float* l3W  = (const float*)d_in[13];
  const float* l3b  = (const float*)d_in[14];

  float* out = (float*)d_out;
  float* tw  = out + (size_t)NB*8;

  // workspace layout
  float* ws    = (float*)d_ws;
  float* stats = ws;                               // NB*24 f32
  float* UV1   = stats + (size_t)NB*24;            // 3*NB*128 f32
  float* UV2   = UV1 + (size_t)3*NB*128;           // 3*NB*128 f32
  float* bp    = UV2 + (size_t)3*NB*128;           // 64 f32
  u16* WpT     = (u16*)(bp + 64);                  // 64*KF bf16
  u16* Wb1     = WpT + (size_t)64*KF;              // 128*1024 bf16
  u16* W2T     = Wb1 + (size_t)128*1024;           // 1024*64 bf16
  u16* Fcat    = W2T + (size_t)1024*64;            // NB*KF bf16

  k1_stats<<<dim3(NB/4), dim3(256), 0, stream>>>(x, attW, attb, stats, Fcat, tw);
  kprew_b1<<<dim3(512), dim3(256), 0, stream>>>(gfW1, Wb1);
  kprew_w2t<<<dim3(256), dim3(256), 0, stream>>>(gfW2, W2T);
  k6_prew<<<dim3(20, 64), dim3(256), 0, stream>>>(bng, l1W, WpT);
  k6_preb<<<dim3(1), dim3(256), 0, stream>>>(bnb, l1W, l1b, bp);

  kg1v2<1><<<dim3(3*NB/64), dim3(256), 0, stream>>>(x, (const u16*)nullptr, Wb1, UV1);
  kL2_mfma<3,0><<<dim3(NB/16, 4), dim3(256), 0, stream>>>(UV1, UV1, W2T, gfb1, gfb2, stats, Fcat);
  k3s_stats2<<<dim3(NB/4), dim3(256), 0, stream>>>(Fcat, x, stats, tw);
  kg1v2<0><<<dim3(3*NB/64), dim3(256), 0, stream>>>((const float*)nullptr, Fcat, Wb1, UV2);
  kL2_mfma<6,1><<<dim3(NB/16, 4), dim3(256), 0, stream>>>(UV2, UV1, W2T, gfb1, gfb2, stats, Fcat);
  k6v2<<<dim3(NB/64), dim3(1024), 0, stream>>>(Fcat, WpT, bp, l2W, l2b, l3W, l3b, out);
}

// Round 5
// 511.857 us; speedup vs baseline: 2.9287x; 1.0983x over previous
//
#include <hip/hip_runtime.h>
#include <math.h>

#define NB 16384
#define DD 1024
#define KF 5120   // concat feature K: uni(1024) + a_v,a_l,v_l(3*1024) + tri(1024)

typedef unsigned short u16;
typedef unsigned int u32;
typedef __attribute__((ext_vector_type(8))) short bf16x8;
typedef __attribute__((ext_vector_type(4))) float f32x4;

// ---------- helpers ----------
__device__ __forceinline__ float bf2f(u16 u){
  return __uint_as_float(((unsigned)u) << 16);
}
__device__ __forceinline__ u16 f2bf(float f){
  unsigned u = __float_as_uint(f);
  return (u16)((u + 0x7fffu + ((u >> 16) & 1u)) >> 16);   // RNE
}
__device__ __forceinline__ u16 f2bf_tr(float f){           // cheap truncate (MFMA inputs only)
  return (u16)(__float_as_uint(f) >> 16);
}
__device__ __forceinline__ float fast_tanh(float x){
  float e = __expf(2.0f * x);
  return 1.0f - 2.0f / (e + 1.0f);
}
__device__ __forceinline__ float wredsum(float x){
  #pragma unroll
  for(int o = 32; o >= 1; o >>= 1) x += __shfl_xor(x, o);
  return x;
}
__device__ __forceinline__ float wredmax(float x){
  #pragma unroll
  for(int o = 32; o >= 1; o >>= 1) x = fmaxf(x, __shfl_xor(x, o));
  return x;
}
__device__ __forceinline__ bf16x8 pack8f(float4 f0, float4 f1){
  bf16x8 r;
  r[0]=(short)f2bf(f0.x); r[1]=(short)f2bf(f0.y); r[2]=(short)f2bf(f0.z); r[3]=(short)f2bf(f0.w);
  r[4]=(short)f2bf(f1.x); r[5]=(short)f2bf(f1.y); r[6]=(short)f2bf(f1.z); r[7]=(short)f2bf(f1.w);
  return r;
}
// async global->LDS, 16B per lane; LDS dest = uniform base + lane*16
__device__ __forceinline__ void gll16(const void* g, void* l){
  __builtin_amdgcn_global_load_lds(
      (const __attribute__((address_space(1))) u32*)g,
      (__attribute__((address_space(3))) u32*)l, 16, 0, 0);
}

// ---------- K1: per-row stats, w_uni, w_bi, unimodal ----------
__global__ __launch_bounds__(256) void k1_stats(
    const float* __restrict__ x, const float* __restrict__ attW,
    const float* __restrict__ attb, float* __restrict__ stats,
    u16* __restrict__ Fcat, float* __restrict__ tw)
{
  int wave = threadIdx.x >> 6, lane = threadIdx.x & 63;
  int r = blockIdx.x * 4 + wave;
  const float* xr = x + (size_t)r * 3 * DD;
  float a[16], v[16], l[16];
  float dA=0.f,dV=0.f,dL=0.f, mA=-1e30f,mV=-1e30f,mL=-1e30f;
  #pragma unroll
  for(int i = 0; i < 16; i++){
    int k = lane + i*64;
    a[i] = xr[k]; v[i] = xr[DD+k]; l[i] = xr[2*DD+k];
    float w = attW[k];
    dA = fmaf(a[i], w, dA); dV = fmaf(v[i], w, dV); dL = fmaf(l[i], w, dL);
    mA = fmaxf(mA, a[i]); mV = fmaxf(mV, v[i]); mL = fmaxf(mL, l[i]);
  }
  dA = wredsum(dA); dV = wredsum(dV); dL = wredsum(dL);
  mA = wredmax(mA); mV = wredmax(mV); mL = wredmax(mL);

  float Sa=0.f,Sv=0.f,Sl=0.f,Eav=0.f,Eal=0.f,Evl=0.f;
  #pragma unroll
  for(int i = 0; i < 16; i++){
    float ea = __expf(a[i]-mA), ev = __expf(v[i]-mV), el = __expf(l[i]-mL);
    Sa += ea; Sv += ev; Sl += el;
    Eav += ea*ev; Eal += ea*el; Evl += ev*el;
  }
  Sa = wredsum(Sa); Sv = wredsum(Sv); Sl = wredsum(Sl);
  Eav = wredsum(Eav); Eal = wredsum(Eal); Evl = wredsum(Evl);

  float ab = attb[0];
  float ta = fast_tanh(dA + ab), tv = fast_tanh(dV + ab), tl = fast_tanh(dL + ab);
  float mm = fmaxf(ta, fmaxf(tv, tl));
  float e0 = __expf(ta-mm), e1 = __expf(tv-mm), e2 = __expf(tl-mm);
  float ss = e0 + e1 + e2;
  float sa = e0/ss, sv = e1/ss, sl = e2/ss;
  float dav = Eav/(Sa*Sv), dal = Eal/(Sa*Sl), dvl = Evl/(Sv*Sl);
  float sav = (sa+sv)/(dav+0.5f);
  float sal = (sa+sl)/(dal+0.5f);
  float svl = (sv+sl)/(dvl+0.5f);
  float m2 = fmaxf(sav, fmaxf(sal, svl));
  float f0 = __expf(sav-m2), f1 = __expf(sal-m2), f2 = __expf(svl-m2);
  float s2 = f0 + f1 + f2;
  float wb0 = f0/s2, wb1 = f1/s2, wb2 = f2/s2;

  if(lane == 0){
    float* st = stats + (size_t)r*24;
    st[0]=sa; st[1]=sv; st[2]=sl;
    st[3]=wb0; st[4]=wb1; st[5]=wb2;
    st[6]=sav; st[7]=sal; st[8]=svl;
    st[9]=mA; st[10]=Sa; st[11]=mV; st[12]=Sv; st[13]=mL; st[14]=Sl;
    float* twr = tw + (size_t)r*12;
    twr[0]=sa; twr[1]=sv; twr[2]=sl; twr[3]=wb0; twr[4]=wb1; twr[5]=wb2;
  }
  #pragma unroll
  for(int i = 0; i < 16; i++){
    int k = lane + i*64;
    Fcat[(size_t)r*KF + k] = f2bf((sa*a[i] + sv*v[i] + sl*l[i]) * (1.0f/3.0f));
  }
}

// ---------- precompute: Wb1 (128 x 1024 bf16): [n][k], n<64 -> U cols, else V ----------
__global__ __launch_bounds__(256) void kprew_b1(
    const float* __restrict__ W1, u16* __restrict__ Wb1)
{
  int idx = blockIdx.x * 256 + threadIdx.x;   // 0..131071
  int n = idx >> 10, k = idx & 1023;
  float v = (n < 64) ? W1[(size_t)k*64 + n] : W1[(size_t)(1024+k)*64 + (n-64)];
  Wb1[idx] = f2bf(v);
}

// ---------- precompute: W2T (1024 x 64 bf16): [c][k] = W2[k][c] ----------
__global__ __launch_bounds__(256) void kprew_w2t(
    const float* __restrict__ W2, u16* __restrict__ W2T)
{
  int idx = blockIdx.x * 256 + threadIdx.x;   // 0..65535
  int c = idx >> 6, k = idx & 63;
  W2T[idx] = f2bf(W2[(size_t)k*DD + c]);
}

// ---------- layer-1 MFMA GEMM: (3NB,1024) @ Wb1^T -> UV (3NB x 128 fp32) ----------
// block: 256 thr / 4 waves; M-tile 64, N=128; waves split N (32 cols each).
// A staged in LDS, double-buffered, XOR-swizzled; B streamed from L2.
template<int FROM_X>
__global__ __launch_bounds__(256) void kg1v2(
    const float* __restrict__ xf, const u16* __restrict__ fc,
    const u16* __restrict__ Wb1, float* __restrict__ UV)
{
  __shared__ u16 Asm[2][64*64];   // 2 x 8KB
  int tid = threadIdx.x;
  int wv = tid >> 6, lane = tid & 63;
  int fr = lane & 15, kg = lane >> 4;
  int mb = blockIdx.x * 64;

  const u16* gsrc0 = nullptr; const u16* gsrc1 = nullptr;
  const float* xsrc0 = nullptr; const float* xsrc1 = nullptr;
  int rr_ = tid >> 3, pp_ = tid & 7;
  int sp_ = pp_ ^ (rr_ & 7);
  if(FROM_X){
    xsrc0 = xf + (size_t)(mb + rr_)*1024 + pp_*8;
    xsrc1 = xf + (size_t)(mb + rr_ + 32)*1024 + pp_*8;
  } else {
    int r8 = lane >> 3, p = lane & 7;
    int sp = p ^ (r8 & 7);
    int m0 = mb + (2*wv)*8 + r8;
    int m1 = mb + (2*wv+1)*8 + r8;
    int R0 = m0/3, R1 = m1/3;
    gsrc0 = fc + (size_t)R0*KF + (size_t)(1 + (m0 - 3*R0))*1024 + sp*8;
    gsrc1 = fc + (size_t)R1*KF + (size_t)(1 + (m1 - 3*R1))*1024 + sp*8;
  }

  f32x4 acc[4][2];
  #pragma unroll
  for(int rf = 0; rf < 4; rf++)
    #pragma unroll
    for(int nf = 0; nf < 2; nf++) acc[rf][nf] = (f32x4){0.f,0.f,0.f,0.f};

  if(FROM_X){
    float4 a0 = *(const float4*)xsrc0, a1 = *(const float4*)(xsrc0+4);
    float4 c0 = *(const float4*)xsrc1, c1 = *(const float4*)(xsrc1+4);
    *(bf16x8*)&Asm[0][rr_*64 + sp_*8]      = pack8f(a0,a1);
    *(bf16x8*)&Asm[0][(rr_+32)*64 + sp_*8] = pack8f(c0,c1);
  } else {
    gll16(gsrc0, &Asm[0][(2*wv)*512]);
    gll16(gsrc1, &Asm[0][(2*wv+1)*512]);
  }
  __syncthreads();

  int buf = 0;
  for(int ci = 0; ci < 16; ci++){
    int k0 = ci*64;
    float4 na0, na1, nc0, nc1;
    if(ci < 15){
      if(FROM_X){
        na0 = *(const float4*)(xsrc0 + k0 + 64); na1 = *(const float4*)(xsrc0 + k0 + 68);
        nc0 = *(const float4*)(xsrc1 + k0 + 64); nc1 = *(const float4*)(xsrc1 + k0 + 68);
      } else {
        gll16(gsrc0 + k0 + 64, &Asm[buf^1][(2*wv)*512]);
        gll16(gsrc1 + k0 + 64, &Asm[buf^1][(2*wv+1)*512]);
      }
    }
    #pragma unroll
    for(int ks = 0; ks < 2; ks++){
      bf16x8 a[4];
      #pragma unroll
      for(int rf = 0; rf < 4; rf++){
        int row = rf*16 + fr;
        int slot = (ks*4 + kg) ^ (fr & 7);
        a[rf] = *(const bf16x8*)&Asm[buf][row*64 + slot*8];
      }
      #pragma unroll
      for(int nf = 0; nf < 2; nf++){
        int col = wv*32 + nf*16 + fr;
        bf16x8 b = *(const bf16x8*)&Wb1[(size_t)col*1024 + k0 + ks*32 + kg*8];
        #pragma unroll
        for(int rf = 0; rf < 4; rf++)
          acc[rf][nf] = __builtin_amdgcn_mfma_f32_16x16x32_bf16(a[rf], b, acc[rf][nf], 0, 0, 0);
      }
    }
    if(FROM_X && ci < 15){
      *(bf16x8*)&Asm[buf^1][rr_*64 + sp_*8]      = pack8f(na0,na1);
      *(bf16x8*)&Asm[buf^1][(rr_+32)*64 + sp_*8] = pack8f(nc0,nc1);
    }
    __syncthreads();
    buf ^= 1;
  }

  #pragma unroll
  for(int rf = 0; rf < 4; rf++)
    #pragma unroll
    for(int nf = 0; nf < 2; nf++)
      #pragma unroll
      for(int q = 0; q < 4; q++)
        UV[(size_t)(mb + rf*16 + kg*4 + q)*128 + wv*32 + nf*16 + fr] = acc[rf][nf][q];
}

// ---------- layer-2 MFMA: t = lrelu(U+V+b1) built in-register from UV ----------
template<int P, int SUM>
__global__ __launch_bounds__(256) void kL2_mfma(
    const float* __restrict__ UVA, const float* __restrict__ UVB,
    const u16* __restrict__ W2T, const float* __restrict__ b1,
    const float* __restrict__ b2, const float* __restrict__ stats,
    u16* __restrict__ Fcat)
{
  int tid = threadIdx.x;
  int wv = tid >> 6, lane = tid & 63;
  int fr = lane & 15, kg = lane >> 4;
  int Rb = blockIdx.x * 16;
  int cb = blockIdx.y * 256 + wv * 64;
  int R = Rb + fr;
  const float* baseA = UVA + (size_t)(3*R)*128;
  const float* baseB = UVB + (size_t)(3*R)*128;

  f32x4 acc[P][4];
  #pragma unroll
  for(int p = 0; p < P; p++)
    #pragma unroll
    for(int cf = 0; cf < 4; cf++) acc[p][cf] = (f32x4){0.f,0.f,0.f,0.f};

  #pragma unroll
  for(int ks = 0; ks < 2; ks++){
    int j0 = ks*32 + kg*8;
    float4 bb0 = *(const float4*)(b1 + j0), bb1 = *(const float4*)(b1 + j0 + 4);
    bf16x8 a[P];
    #pragma unroll
    for(int p = 0; p < P; p++){
      int up, vp;
      const float* VBb;
      if(P == 3){
        up = (p == 2) ? 1 : 0;           // a1,a1,v1
        vp = (p == 0) ? 1 : 2;           // v1,l1,l1
        VBb = baseA;
      } else {
        up = (0x210200 >> (p*4)) & 15;   // a_v,a_v,v_l,a_v,a_l,v_l
        vp = (0x012112 >> (p*4)) & 15;   // v_l,a_l,a_l,l1,v1,a1
        VBb = (p < 3) ? baseA : baseB;
      }
      const float* Up = baseA + (size_t)up*128 + j0;
      const float* Vp = VBb  + (size_t)vp*128 + 64 + j0;
      float4 u0 = *(const float4*)Up, u1 = *(const float4*)(Up+4);
      float4 v0 = *(const float4*)Vp, v1 = *(const float4*)(Vp+4);
      float t[8] = {u0.x+v0.x+bb0.x, u0.y+v0.y+bb0.y, u0.z+v0.z+bb0.z, u0.w+v0.w+bb0.w,
                    u1.x+v1.x+bb1.x, u1.y+v1.y+bb1.y, u1.z+v1.z+bb1.z, u1.w+v1.w+bb1.w};
      bf16x8 o;
      #pragma unroll
      for(int j = 0; j < 8; j++){
        float tv = t[j] > 0.f ? t[j] : 0.2f*t[j];
        o[j] = (short)f2bf_tr(tv);
      }
      a[p] = o;
    }
    #pragma unroll
    for(int cf = 0; cf < 4; cf++){
      bf16x8 b = *(const bf16x8*)&W2T[(size_t)(cb + cf*16 + fr)*64 + j0];
      #pragma unroll
      for(int p = 0; p < P; p++)
        acc[p][cf] = __builtin_amdgcn_mfma_f32_16x16x32_bf16(a[p], b, acc[p][cf], 0, 0, 0);
    }
  }

  #pragma unroll
  for(int q = 0; q < 4; q++){
    int Rq = Rb + kg*4 + q;
    const float* st = stats + (size_t)Rq*24;
    #pragma unroll
    for(int cf = 0; cf < 4; cf++){
      int c = cb + cf*16 + fr;
      float b2c = b2[c];
      if(SUM){
        float s = 0.f;
        #pragma unroll
        for(int p = 0; p < P; p++){
          float g = st[15+p] * fast_tanh(acc[p][cf][q] + b2c);
          s += g > 0.f ? g : 0.01f*g;
        }
        Fcat[(size_t)Rq*KF + 4096 + c] = f2bf(s * (1.0f/6.0f));
      } else {
        #pragma unroll
        for(int p = 0; p < P; p++){
          float g = st[3+p] * fast_tanh(acc[p][cf][q] + b2c);
          float val = g > 0.f ? g : 0.01f*g;
          Fcat[(size_t)Rq*KF + (size_t)(1+p)*1024 + c] = f2bf(val);
        }
      }
    }
  }
}

// ---------- K3s: softmax stats of a_v/a_l/v_l + cross dots -> w_tri ----------
__global__ __launch_bounds__(256) void k3s_stats2(
    const u16* __restrict__ Fcat, const float* __restrict__ x,
    float* __restrict__ stats, float* __restrict__ tw)
{
  int wave = threadIdx.x >> 6, lane = threadIdx.x & 63;
  int r = blockIdx.x * 4 + wave;
  const u16*   pv = Fcat + (size_t)r*KF + 1024;
  const float* xr = x    + (size_t)3*r*DD;
  float av[16], al[16], vl[16];
  float mav=-1e30f, mal=-1e30f, mvl=-1e30f;
  #pragma unroll
  for(int i = 0; i < 16; i++){
    int k = lane + i*64;
    av[i] = bf2f(pv[k]); al[i] = bf2f(pv[DD+k]); vl[i] = bf2f(pv[2*DD+k]);
    mav = fmaxf(mav, av[i]); mal = fmaxf(mal, al[i]); mvl = fmaxf(mvl, vl[i]);
  }
  mav = wredmax(mav); mal = wredmax(mal); mvl = wredmax(mvl);

  float* st = stats + (size_t)r*24;
  float sa=st[0], sv=st[1], sl=st[2];
  float sav=st[6], sal=st[7], svl=st[8];
  float mA=st[9], Sa=st[10], mV=st[11], Sv=st[12], mL=st[13], Sl=st[14];

  float Savv=0.f,Sall=0.f,Svll=0.f,E1=0.f,E2=0.f,E3=0.f,E4=0.f,E5=0.f,E6=0.f;
  #pragma unroll
  for(int i = 0; i < 16; i++){
    int k = lane + i*64;
    float a1 = xr[k], v1 = xr[DD+k], l1 = xr[2*DD+k];
    float eav = __expf(av[i]-mav), eal = __expf(al[i]-mal), evl = __expf(vl[i]-mvl);
    Savv += eav; Sall += eal; Svll += evl;
    float ea = __expf(a1-mA), ev = __expf(v1-mV), el = __expf(l1-mL);
    E1 += eav*evl; E2 += eav*eal; E3 += eal*evl;
    E4 += eav*el;  E5 += eal*ev;  E6 += evl*ea;
  }
  Savv = wredsum(Savv); Sall = wredsum(Sall); Svll = wredsum(Svll);
  E1 = wredsum(E1); E2 = wredsum(E2); E3 = wredsum(E3);
  E4 = wredsum(E4); E5 = wredsum(E5); E6 = wredsum(E6);

  float d1 = E1/(Savv*Svll), d2 = E2/(Savv*Sall), d3 = E3/(Sall*Svll);
  float d4 = E4/(Savv*Sl),   d5 = E5/(Sall*Sv),   d6 = E6/(Svll*Sa);
  float t0 = (sav+svl)/(d1+0.5f);
  float t1 = (sav+sal)/(d2+0.5f);
  float t2 = (sal+svl)/(d3+0.5f);
  float t3 = (sav+sl)/(d4+0.5f);
  float t4 = (sal+sv)/(d5+0.5f);
  float t5 = (sa+svl)/(d6+0.5f);
  float mx = fmaxf(fmaxf(fmaxf(t0,t1),fmaxf(t2,t3)),fmaxf(t4,t5));
  float g0=__expf(t0-mx),g1=__expf(t1-mx),g2=__expf(t2-mx);
  float g3=__expf(t3-mx),g4=__expf(t4-mx),g5=__expf(t5-mx);
  float gs = g0+g1+g2+g3+g4+g5;
  if(lane == 0){
    float wt[6] = {g0/gs,g1/gs,g2/gs,g3/gs,g4/gs,g5/gs};
    float* twr = tw + (size_t)r*12;
    #pragma unroll
    for(int p = 0; p < 6; p++){ st[15+p] = wt[p]; twr[6+p] = wt[p]; }
  }
}

// ---------- K6 precompute: WpT (64 x 5120 bf16), BN folded ----------
__global__ __launch_bounds__(256) void k6_prew(
    const float* __restrict__ gamma, const float* __restrict__ l1W,
    u16* __restrict__ WpT)
{
  int kk = blockIdx.x * 256 + threadIdx.x;   // 0..5119 (grid.x = 20)
  int j  = blockIdx.y;                        // 0..63
  const float gsc = 1.0f / sqrtf(1.0f + 1e-5f);
  int korig; float sc;
  if(kk < 1024){ korig = kk; sc = 1.f; }
  else if(kk < 4096){ korig = 1024 + ((kk - 1024) & 1023); sc = 1.0f/3.0f; }
  else { korig = 2048 + (kk - 4096); sc = 1.f; }
  float v = (j < 50) ? l1W[(size_t)korig*50 + j] * gamma[korig] * gsc * sc : 0.f;
  WpT[(size_t)j*KF + kk] = f2bf(v);
}

// ---------- K6 precompute: bp[j] = l1b[j] + beta @ l1W ----------
__global__ __launch_bounds__(256) void k6_preb(
    const float* __restrict__ beta, const float* __restrict__ l1W,
    const float* __restrict__ l1b, float* __restrict__ bp)
{
  __shared__ float red[4][64];
  int j = threadIdx.x & 63, seg = threadIdx.x >> 6;
  float s = 0.f;
  if(j < 50){
    for(int k = seg*768; k < seg*768 + 768; k++)
      s = fmaf(beta[k], l1W[(size_t)k*50 + j], s);
  }
  red[seg][j] = s;
  __syncthreads();
  if(seg == 0){
    float t = red[0][j] + red[1][j] + red[2][j] + red[3][j];
    bp[j] = (j < 50) ? (l1b[j] + t) : 0.f;
  }
}

// ---------- K6 v3: (NB x 5120)@(5120 x 64) + MLP tail ----------
// M-tile 32, 256 thr / 4 waves; wave = 16-col fragment, full K (no K-split).
// A LDS-staged (gll16, XOR-swizzle), double-buffered, 1 barrier/chunk.
__global__ __launch_bounds__(256) void k6v3(
    const u16* __restrict__ Fcat, const u16* __restrict__ WpT,
    const float* __restrict__ bp,
    const float* __restrict__ l2W, const float* __restrict__ l2b,
    const float* __restrict__ l3W, const float* __restrict__ l3b,
    float* __restrict__ y2out)
{
  __shared__ __align__(16) char smem[29760];
  u16*  Asm = (u16*)smem;                          // [2][2048] = 8 KB (stage)
  float* W2s = (float*)(smem + 8192);              // [50][64]  = 12.8 KB
  float* W3s = (float*)(smem + 8192 + 12800);      // [50][8]   = 1.6 KB
  float* Ys  = (float*)smem;                       // [32][56]  aliases Asm (7 KB)
  float* Ys2 = (float*)(smem + 8192 + 12800 + 1600); // [32][56] = 7 KB

  int tid = threadIdx.x;
  int wv = tid >> 6, lane = tid & 63;
  int fr = lane & 15, kg = lane >> 4;
  int rb = blockIdx.x * 32;

  // stage small tail weights (non-aliased region)
  for(int t = tid; t < 3200; t += 256){
    int c = t & 63;
    W2s[t] = (c < 50) ? l2W[(t >> 6)*50 + c] : 0.f;
  }
  for(int t = tid; t < 400; t += 256) W3s[t] = l3W[t];

  // gll16 source: lane l stages row (wv*8 + l>>3), physical slot (l&7),
  // source k-part sp = (l&7) ^ (l>>3)   [XOR-swizzle, involution]
  int r8 = lane >> 3, pp = lane & 7;
  int sp = pp ^ r8;
  const u16* gsrc = Fcat + (size_t)(rb + wv*8 + r8)*KF + sp*8;
  const u16* bptr = WpT  + (size_t)(fr)*KF + (size_t)wv*16*KF + kg*8;

  f32x4 acc[2];
  acc[0] = (f32x4){0.f,0.f,0.f,0.f};
  acc[1] = (f32x4){0.f,0.f,0.f,0.f};

  gll16(gsrc, &Asm[wv*512]);
  __syncthreads();

  int buf = 0;
  for(int ci = 0; ci < 80; ci++){
    int k0 = ci*64;
    if(ci < 79)
      gll16(gsrc + k0 + 64, &Asm[(buf^1)*2048 + wv*512]);
    #pragma unroll
    for(int ks = 0; ks < 2; ks++){
      bf16x8 b = *(const bf16x8*)(bptr + k0 + ks*32);
      #pragma unroll
      for(int rf = 0; rf < 2; rf++){
        int row = rf*16 + fr;
        int slot = (ks*4 + kg) ^ (fr & 7);
        bf16x8 a = *(const bf16x8*)&Asm[buf*2048 + row*64 + slot*8];
        acc[rf] = __builtin_amdgcn_mfma_f32_16x16x32_bf16(a, b, acc[rf], 0, 0, 0);
      }
    }
    __syncthreads();
    buf ^= 1;
  }

  // epilogue: Ys[row][col] = tanh(acc + bp)   (aliases Asm -- after final barrier)
  {
    int col = wv*16 + fr;
    float bpc = bp[col];
    #pragma unroll
    for(int rf = 0; rf < 2; rf++)
      #pragma unroll
      for(int q = 0; q < 4; q++){
        int row = rf*16 + kg*4 + q;
        if(col < 50) Ys[row*56 + col] = fast_tanh(acc[rf][q] + bpc);
      }
  }
  __syncthreads();

  // stage 2: Ys(32x50) @ W2 -> tanh -> Ys2 ; thread = (row, 7-col group)
  {
    int r = tid >> 3, cg = (tid & 7) * 7;   // cols cg..cg+6 (covers 0..55)
    float a2[7] = {0,0,0,0,0,0,0};
    for(int k = 0; k < 50; k++){
      float yv = Ys[r*56 + k];
      #pragma unroll
      for(int c = 0; c < 7; c++) a2[c] = fmaf(yv, W2s[k*64 + cg + c], a2[c]);
    }
    #pragma unroll
    for(int c = 0; c < 7; c++){
      int cc = cg + c;
      if(cc < 50) Ys2[r*56 + cc] = fast_tanh(a2[c] + l2b[cc]);
    }
  }
  __syncthreads();

  // stage 3: Ys2(32x50) @ W3 + b3, softmax over 8
  {
    int r = tid >> 3, c = tid & 7;
    float z = l3b[c];
    for(int k = 0; k < 50; k++) z = fmaf(Ys2[r*56 + k], W3s[k*8 + c], z);
    float m = z;
    m = fmaxf(m, __shfl_xor(m, 1));
    m = fmaxf(m, __shfl_xor(m, 2));
    m = fmaxf(m, __shfl_xor(m, 4));
    float e = __expf(z - m);
    float s = e;
    s += __shfl_xor(s, 1); s += __shfl_xor(s, 2); s += __shfl_xor(s, 4);
    y2out[(size_t)(rb + r)*8 + c] = e / s;
  }
}

// ---------- launch ----------
extern "C" void kernel_launch(void* const* d_in, const int* in_sizes, int n_in,
                              void* d_out, int out_size, void* d_ws, size_t ws_size,
                              hipStream_t stream)
{
  (void)in_sizes; (void)n_in; (void)out_size; (void)ws_size;
  const float* x    = (const float*)d_in[0];
  const float* attW = (const float*)d_in[1];
  const float* attb = (const float*)d_in[2];
  const float* gfW1 = (const float*)d_in[3];
  const float* gfb1 = (const float*)d_in[4];
  const float* gfW2 = (const float*)d_in[5];
  const float* gfb2 = (const float*)d_in[6];
  const float* bng  = (const float*)d_in[7];
  const float* bnb  = (const float*)d_in[8];
  const float* l1W  = (const float*)d_in[9];
  const float* l1b  = (const float*)d_in[10];
  const float* l2W  = (const float*)d_in[11];
  const float* l2b  = (const float*)d_in[12];
  const float* l3W  = (const float*)d_in[13];
  const float* l3b  = (const float*)d_in[14];

  float* out = (float*)d_out;
  float* tw  = out + (size_t)NB*8;

  // workspace layout
  float* ws    = (float*)d_ws;
  float* stats = ws;                               // NB*24 f32
  float* UV1   = stats + (size_t)NB*24;            // 3*NB*128 f32
  float* UV2   = UV1 + (size_t)3*NB*128;           // 3*NB*128 f32
  float* bp    = UV2 + (size_t)3*NB*128;           // 64 f32
  u16* WpT     = (u16*)(bp + 64);                  // 64*KF bf16
  u16* Wb1     = WpT + (size_t)64*KF;              // 128*1024 bf16
  u16* W2T     = Wb1 + (size_t)128*1024;           // 1024*64 bf16
  u16* Fcat    = W2T + (size_t)1024*64;            // NB*KF bf16

  k1_stats<<<dim3(NB/4), dim3(256), 0, stream>>>(x, attW, attb, stats, Fcat, tw);
  kprew_b1<<<dim3(512), dim3(256), 0, stream>>>(gfW1, Wb1);
  kprew_w2t<<<dim3(256), dim3(256), 0, stream>>>(gfW2, W2T);
  k6_prew<<<dim3(20, 64), dim3(256), 0, stream>>>(bng, l1W, WpT);
  k6_preb<<<dim3(1), dim3(256), 0, stream>>>(bnb, l1W, l1b, bp);

  kg1v2<1><<<dim3(3*NB/64), dim3(256), 0, stream>>>(x, (const u16*)nullptr, Wb1, UV1);
  kL2_mfma<3,0><<<dim3(NB/16, 4), dim3(256), 0, stream>>>(UV1, UV1, W2T, gfb1, gfb2, stats, Fcat);
  k3s_stats2<<<dim3(NB/4), dim3(256), 0, stream>>>(Fcat, x, stats, tw);
  kg1v2<0><<<dim3(3*NB/64), dim3(256), 0, stream>>>((const float*)nullptr, Fcat, Wb1, UV2);
  kL2_mfma<6,1><<<dim3(NB/16, 4), dim3(256), 0, stream>>>(UV2, UV1, W2T, gfb1, gfb2, stats, Fcat);
  k6v3<<<dim3(NB/32), dim3(256), 0, stream>>>(Fcat, WpT, bp, l2W, l2b, l3W, l3b, out);
}

// Round 6
// 424.479 us; speedup vs baseline: 3.5316x; 1.2058x over previous
//
#include <hip/hip_runtime.h>
#include <math.h>

#define NB 16384
#define DD 1024
#define KF 5120   // concat feature K: uni(1024) + a_v,a_l,v_l(3*1024) + tri(1024)

typedef unsigned short u16;
typedef unsigned int u32;
typedef __attribute__((ext_vector_type(8))) short bf16x8;
typedef __attribute__((ext_vector_type(4))) float f32x4;

// ---------- helpers ----------
__device__ __forceinline__ float bf2f(u16 u){
  return __uint_as_float(((unsigned)u) << 16);
}
__device__ __forceinline__ u16 f2bf(float f){
  unsigned u = __float_as_uint(f);
  return (u16)((u + 0x7fffu + ((u >> 16) & 1u)) >> 16);   // RNE
}
__device__ __forceinline__ u16 f2bf_tr(float f){           // cheap truncate (MFMA inputs only)
  return (u16)(__float_as_uint(f) >> 16);
}
__device__ __forceinline__ float fast_tanh(float x){
  float e = __expf(2.0f * x);
  return 1.0f - 2.0f * __builtin_amdgcn_rcpf(e + 1.0f);
}
__device__ __forceinline__ float wredsum(float x){
  #pragma unroll
  for(int o = 32; o >= 1; o >>= 1) x += __shfl_xor(x, o);
  return x;
}
__device__ __forceinline__ float wredmax(float x){
  #pragma unroll
  for(int o = 32; o >= 1; o >>= 1) x = fmaxf(x, __shfl_xor(x, o));
  return x;
}
__device__ __forceinline__ bf16x8 pack8f(float4 f0, float4 f1){
  bf16x8 r;
  r[0]=(short)f2bf(f0.x); r[1]=(short)f2bf(f0.y); r[2]=(short)f2bf(f0.z); r[3]=(short)f2bf(f0.w);
  r[4]=(short)f2bf(f1.x); r[5]=(short)f2bf(f1.y); r[6]=(short)f2bf(f1.z); r[7]=(short)f2bf(f1.w);
  return r;
}
// async global->LDS, 16B per lane; LDS dest = uniform base + lane*16
__device__ __forceinline__ void gll16(const void* g, void* l){
  __builtin_amdgcn_global_load_lds(
      (const __attribute__((address_space(1))) u32*)g,
      (__attribute__((address_space(3))) u32*)l, 16, 0, 0);
}

// ---------- K1: per-row stats, w_uni, w_bi, unimodal ----------
__global__ __launch_bounds__(256) void k1_stats(
    const float* __restrict__ x, const float* __restrict__ attW,
    const float* __restrict__ attb, float* __restrict__ stats,
    u16* __restrict__ Fcat, float* __restrict__ tw)
{
  int wave = threadIdx.x >> 6, lane = threadIdx.x & 63;
  int r = blockIdx.x * 4 + wave;
  const float* xr = x + (size_t)r * 3 * DD;
  float a[16], v[16], l[16];
  float dA=0.f,dV=0.f,dL=0.f, mA=-1e30f,mV=-1e30f,mL=-1e30f;
  #pragma unroll
  for(int i = 0; i < 16; i++){
    int k = lane + i*64;
    a[i] = xr[k]; v[i] = xr[DD+k]; l[i] = xr[2*DD+k];
    float w = attW[k];
    dA = fmaf(a[i], w, dA); dV = fmaf(v[i], w, dV); dL = fmaf(l[i], w, dL);
    mA = fmaxf(mA, a[i]); mV = fmaxf(mV, v[i]); mL = fmaxf(mL, l[i]);
  }
  dA = wredsum(dA); dV = wredsum(dV); dL = wredsum(dL);
  mA = wredmax(mA); mV = wredmax(mV); mL = wredmax(mL);

  float Sa=0.f,Sv=0.f,Sl=0.f,Eav=0.f,Eal=0.f,Evl=0.f;
  #pragma unroll
  for(int i = 0; i < 16; i++){
    float ea = __expf(a[i]-mA), ev = __expf(v[i]-mV), el = __expf(l[i]-mL);
    Sa += ea; Sv += ev; Sl += el;
    Eav += ea*ev; Eal += ea*el; Evl += ev*el;
  }
  Sa = wredsum(Sa); Sv = wredsum(Sv); Sl = wredsum(Sl);
  Eav = wredsum(Eav); Eal = wredsum(Eal); Evl = wredsum(Evl);

  float ab = attb[0];
  float ta = fast_tanh(dA + ab), tv = fast_tanh(dV + ab), tl = fast_tanh(dL + ab);
  float mm = fmaxf(ta, fmaxf(tv, tl));
  float e0 = __expf(ta-mm), e1 = __expf(tv-mm), e2 = __expf(tl-mm);
  float ss = e0 + e1 + e2;
  float sa = e0/ss, sv = e1/ss, sl = e2/ss;
  float dav = Eav/(Sa*Sv), dal = Eal/(Sa*Sl), dvl = Evl/(Sv*Sl);
  float sav = (sa+sv)/(dav+0.5f);
  float sal = (sa+sl)/(dal+0.5f);
  float svl = (sv+sl)/(dvl+0.5f);
  float m2 = fmaxf(sav, fmaxf(sal, svl));
  float f0 = __expf(sav-m2), f1 = __expf(sal-m2), f2 = __expf(svl-m2);
  float s2 = f0 + f1 + f2;
  float wb0 = f0/s2, wb1 = f1/s2, wb2 = f2/s2;

  if(lane == 0){
    float* st = stats + (size_t)r*24;
    st[0]=sa; st[1]=sv; st[2]=sl;
    st[3]=wb0; st[4]=wb1; st[5]=wb2;
    st[6]=sav; st[7]=sal; st[8]=svl;
    st[9]=mA; st[10]=Sa; st[11]=mV; st[12]=Sv; st[13]=mL; st[14]=Sl;
    float* twr = tw + (size_t)r*12;
    twr[0]=sa; twr[1]=sv; twr[2]=sl; twr[3]=wb0; twr[4]=wb1; twr[5]=wb2;
  }
  #pragma unroll
  for(int i = 0; i < 16; i++){
    int k = lane + i*64;
    Fcat[(size_t)r*KF + k] = f2bf((sa*a[i] + sv*v[i] + sl*l[i]) * (1.0f/3.0f));
  }
}

// ---------- precompute: Wb1 (128 x 1024 bf16): [n][k], n<64 -> U cols, else V ----------
__global__ __launch_bounds__(256) void kprew_b1(
    const float* __restrict__ W1, u16* __restrict__ Wb1)
{
  int idx = blockIdx.x * 256 + threadIdx.x;   // 0..131071
  int n = idx >> 10, k = idx & 1023;
  float v = (n < 64) ? W1[(size_t)k*64 + n] : W1[(size_t)(1024+k)*64 + (n-64)];
  Wb1[idx] = f2bf(v);
}

// ---------- precompute: W2T (1024 x 64 bf16): [c][k] = W2[k][c] ----------
__global__ __launch_bounds__(256) void kprew_w2t(
    const float* __restrict__ W2, u16* __restrict__ W2T)
{
  int idx = blockIdx.x * 256 + threadIdx.x;   // 0..65535
  int c = idx >> 6, k = idx & 63;
  W2T[idx] = f2bf(W2[(size_t)k*DD + c]);
}

// ---------- layer-1 MFMA GEMM: (3NB,1024) @ Wb1^T -> UV (3NB x 128 fp32) ----------
template<int FROM_X>
__global__ __launch_bounds__(256) void kg1v2(
    const float* __restrict__ xf, const u16* __restrict__ fc,
    const u16* __restrict__ Wb1, float* __restrict__ UV)
{
  __shared__ u16 Asm[2][64*64];   // 2 x 8KB
  int tid = threadIdx.x;
  int wv = tid >> 6, lane = tid & 63;
  int fr = lane & 15, kg = lane >> 4;
  int mb = blockIdx.x * 64;

  const u16* gsrc0 = nullptr; const u16* gsrc1 = nullptr;
  const float* xsrc0 = nullptr; const float* xsrc1 = nullptr;
  int rr_ = tid >> 3, pp_ = tid & 7;
  int sp_ = pp_ ^ (rr_ & 7);
  if(FROM_X){
    xsrc0 = xf + (size_t)(mb + rr_)*1024 + pp_*8;
    xsrc1 = xf + (size_t)(mb + rr_ + 32)*1024 + pp_*8;
  } else {
    int r8 = lane >> 3, p = lane & 7;
    int sp = p ^ (r8 & 7);
    int m0 = mb + (2*wv)*8 + r8;
    int m1 = mb + (2*wv+1)*8 + r8;
    int R0 = m0/3, R1 = m1/3;
    gsrc0 = fc + (size_t)R0*KF + (size_t)(1 + (m0 - 3*R0))*1024 + sp*8;
    gsrc1 = fc + (size_t)R1*KF + (size_t)(1 + (m1 - 3*R1))*1024 + sp*8;
  }

  f32x4 acc[4][2];
  #pragma unroll
  for(int rf = 0; rf < 4; rf++)
    #pragma unroll
    for(int nf = 0; nf < 2; nf++) acc[rf][nf] = (f32x4){0.f,0.f,0.f,0.f};

  if(FROM_X){
    float4 a0 = *(const float4*)xsrc0, a1 = *(const float4*)(xsrc0+4);
    float4 c0 = *(const float4*)xsrc1, c1 = *(const float4*)(xsrc1+4);
    *(bf16x8*)&Asm[0][rr_*64 + sp_*8]      = pack8f(a0,a1);
    *(bf16x8*)&Asm[0][(rr_+32)*64 + sp_*8] = pack8f(c0,c1);
  } else {
    gll16(gsrc0, &Asm[0][(2*wv)*512]);
    gll16(gsrc1, &Asm[0][(2*wv+1)*512]);
  }
  __syncthreads();

  int buf = 0;
  for(int ci = 0; ci < 16; ci++){
    int k0 = ci*64;
    float4 na0, na1, nc0, nc1;
    if(ci < 15){
      if(FROM_X){
        na0 = *(const float4*)(xsrc0 + k0 + 64); na1 = *(const float4*)(xsrc0 + k0 + 68);
        nc0 = *(const float4*)(xsrc1 + k0 + 64); nc1 = *(const float4*)(xsrc1 + k0 + 68);
      } else {
        gll16(gsrc0 + k0 + 64, &Asm[buf^1][(2*wv)*512]);
        gll16(gsrc1 + k0 + 64, &Asm[buf^1][(2*wv+1)*512]);
      }
    }
    #pragma unroll
    for(int ks = 0; ks < 2; ks++){
      bf16x8 a[4];
      #pragma unroll
      for(int rf = 0; rf < 4; rf++){
        int row = rf*16 + fr;
        int slot = (ks*4 + kg) ^ (fr & 7);
        a[rf] = *(const bf16x8*)&Asm[buf][row*64 + slot*8];
      }
      #pragma unroll
      for(int nf = 0; nf < 2; nf++){
        int col = wv*32 + nf*16 + fr;
        bf16x8 b = *(const bf16x8*)&Wb1[(size_t)col*1024 + k0 + ks*32 + kg*8];
        #pragma unroll
        for(int rf = 0; rf < 4; rf++)
          acc[rf][nf] = __builtin_amdgcn_mfma_f32_16x16x32_bf16(a[rf], b, acc[rf][nf], 0, 0, 0);
      }
    }
    if(FROM_X && ci < 15){
      *(bf16x8*)&Asm[buf^1][rr_*64 + sp_*8]      = pack8f(na0,na1);
      *(bf16x8*)&Asm[buf^1][(rr_+32)*64 + sp_*8] = pack8f(nc0,nc1);
    }
    __syncthreads();
    buf ^= 1;
  }

  #pragma unroll
  for(int rf = 0; rf < 4; rf++)
    #pragma unroll
    for(int nf = 0; nf < 2; nf++)
      #pragma unroll
      for(int q = 0; q < 4; q++)
        UV[(size_t)(mb + rf*16 + kg*4 + q)*128 + wv*32 + nf*16 + fr] = acc[rf][nf][q];
}

// ---------- layer-2 MFMA v2: cooperative LDS t-build + LDS A-fragments ----------
// block: 16 rows x 256 cols, 4 waves (64 cols each), P pairs.
template<int P, int SUM>
__global__ __launch_bounds__(256) void kL2v2(
    const float* __restrict__ UVA, const float* __restrict__ UVB,
    const u16* __restrict__ W2T, const float* __restrict__ b1,
    const float* __restrict__ b2, const float* __restrict__ stats,
    u16* __restrict__ Fcat)
{
  __shared__ u16 Tsm[P][16][64];   // bf16, XOR-swizzled 16B slots
  __shared__ float stw[16][8];
  int tid = threadIdx.x;
  int wv = tid >> 6, lane = tid & 63;
  int fr = lane & 15, kg = lane >> 4;
  int Rb = blockIdx.x * 16;
  int cb = blockIdx.y * 256 + wv * 64;

  // ---- phase 1: t = lrelu0.2(U+V+b1) -> Tsm (cooperative, coalesced) ----
  const int NG = P*16*8;           // (p, r, g) work items, 8 elems each
  for(int i = tid; i < NG; i += 256){
    int g = i & 7, r = (i >> 3) & 15, p = i >> 7;
    int R = Rb + r;
    int up, vp; const float* VBb;
    if(P == 3){
      up = (p == 2) ? 1 : 0;           // a1,a1,v1
      vp = (p == 0) ? 1 : 2;           // v1,l1,l1
      VBb = UVA;
    } else {
      up = (0x210200 >> (p*4)) & 15;   // a_v,a_v,v_l,a_v,a_l,v_l
      vp = (0x012112 >> (p*4)) & 15;   // v_l,a_l,a_l,l1,v1,a1
      VBb = (p < 3) ? UVA : UVB;
    }
    const float* Up = UVA + (size_t)(3*R + up)*128 + g*8;
    const float* Vp = VBb + (size_t)(3*R + vp)*128 + 64 + g*8;
    float4 u0 = *(const float4*)Up, u1 = *(const float4*)(Up+4);
    float4 v0 = *(const float4*)Vp, v1 = *(const float4*)(Vp+4);
    float4 bb0 = *(const float4*)(b1 + g*8), bb1 = *(const float4*)(b1 + g*8 + 4);
    float t[8] = {u0.x+v0.x+bb0.x, u0.y+v0.y+bb0.y, u0.z+v0.z+bb0.z, u0.w+v0.w+bb0.w,
                  u1.x+v1.x+bb1.x, u1.y+v1.y+bb1.y, u1.z+v1.z+bb1.z, u1.w+v1.w+bb1.w};
    bf16x8 o;
    #pragma unroll
    for(int j = 0; j < 8; j++){
      float tv = t[j] > 0.f ? t[j] : 0.2f*t[j];
      o[j] = (short)f2bf_tr(tv);
    }
    *(bf16x8*)&Tsm[p][r][(g ^ (r & 7))*8] = o;
  }
  if(tid < 16*P){
    int r = tid / P, p = tid - r*P;
    stw[r][p] = stats[(size_t)(Rb + r)*24 + (SUM ? 15 : 3) + p];
  }
  __syncthreads();

  // ---- phase 2: MFMA (A from LDS, B from global/L1) ----
  f32x4 acc[P][4];
  #pragma unroll
  for(int p = 0; p < P; p++)
    #pragma unroll
    for(int cf = 0; cf < 4; cf++) acc[p][cf] = (f32x4){0.f,0.f,0.f,0.f};

  #pragma unroll
  for(int ks = 0; ks < 2; ks++){
    bf16x8 a[P];
    #pragma unroll
    for(int p = 0; p < P; p++)
      a[p] = *(const bf16x8*)&Tsm[p][fr][(((ks<<2)+kg) ^ (fr & 7))*8];
    #pragma unroll
    for(int cf = 0; cf < 4; cf++){
      bf16x8 b = *(const bf16x8*)&W2T[(size_t)(cb + cf*16 + fr)*64 + ks*32 + kg*8];
      #pragma unroll
      for(int p = 0; p < P; p++)
        acc[p][cf] = __builtin_amdgcn_mfma_f32_16x16x32_bf16(a[p], b, acc[p][cf], 0, 0, 0);
    }
  }

  // ---- phase 3: epilogue ----
  #pragma unroll
  for(int q = 0; q < 4; q++){
    int Rq = Rb + kg*4 + q;
    #pragma unroll
    for(int cf = 0; cf < 4; cf++){
      int c = cb + cf*16 + fr;
      float b2c = b2[c];
      if(SUM){
        float s = 0.f;
        #pragma unroll
        for(int p = 0; p < P; p++){
          float g = stw[kg*4+q][p] * fast_tanh(acc[p][cf][q] + b2c);
          s += g > 0.f ? g : 0.01f*g;
        }
        Fcat[(size_t)Rq*KF + 4096 + c] = f2bf(s * (1.0f/6.0f));
      } else {
        #pragma unroll
        for(int p = 0; p < P; p++){
          float g = stw[kg*4+q][p] * fast_tanh(acc[p][cf][q] + b2c);
          float val = g > 0.f ? g : 0.01f*g;
          Fcat[(size_t)Rq*KF + (size_t)(1+p)*1024 + c] = f2bf(val);
        }
      }
    }
  }
}

// ---------- K3s: softmax stats of a_v/a_l/v_l + cross dots -> w_tri ----------
__global__ __launch_bounds__(256) void k3s_stats2(
    const u16* __restrict__ Fcat, const float* __restrict__ x,
    float* __restrict__ stats, float* __restrict__ tw)
{
  int wave = threadIdx.x >> 6, lane = threadIdx.x & 63;
  int r = blockIdx.x * 4 + wave;
  const u16*   pv = Fcat + (size_t)r*KF + 1024;
  const float* xr = x    + (size_t)3*r*DD;
  float av[16], al[16], vl[16];
  float mav=-1e30f, mal=-1e30f, mvl=-1e30f;
  #pragma unroll
  for(int i = 0; i < 16; i++){
    int k = lane + i*64;
    av[i] = bf2f(pv[k]); al[i] = bf2f(pv[DD+k]); vl[i] = bf2f(pv[2*DD+k]);
    mav = fmaxf(mav, av[i]); mal = fmaxf(mal, al[i]); mvl = fmaxf(mvl, vl[i]);
  }
  mav = wredmax(mav); mal = wredmax(mal); mvl = wredmax(mvl);

  float* st = stats + (size_t)r*24;
  float sa=st[0], sv=st[1], sl=st[2];
  float sav=st[6], sal=st[7], svl=st[8];
  float mA=st[9], Sa=st[10], mV=st[11], Sv=st[12], mL=st[13], Sl=st[14];

  float Savv=0.f,Sall=0.f,Svll=0.f,E1=0.f,E2=0.f,E3=0.f,E4=0.f,E5=0.f,E6=0.f;
  #pragma unroll
  for(int i = 0; i < 16; i++){
    int k = lane + i*64;
    float a1 = xr[k], v1 = xr[DD+k], l1 = xr[2*DD+k];
    float eav = __expf(av[i]-mav), eal = __expf(al[i]-mal), evl = __expf(vl[i]-mvl);
    Savv += eav; Sall += eal; Svll += evl;
    float ea = __expf(a1-mA), ev = __expf(v1-mV), el = __expf(l1-mL);
    E1 += eav*evl; E2 += eav*eal; E3 += eal*evl;
    E4 += eav*el;  E5 += eal*ev;  E6 += evl*ea;
  }
  Savv = wredsum(Savv); Sall = wredsum(Sall); Svll = wredsum(Svll);
  E1 = wredsum(E1); E2 = wredsum(E2); E3 = wredsum(E3);
  E4 = wredsum(E4); E5 = wredsum(E5); E6 = wredsum(E6);

  float d1 = E1/(Savv*Svll), d2 = E2/(Savv*Sall), d3 = E3/(Sall*Svll);
  float d4 = E4/(Savv*Sl),   d5 = E5/(Sall*Sv),   d6 = E6/(Svll*Sa);
  float t0 = (sav+svl)/(d1+0.5f);
  float t1 = (sav+sal)/(d2+0.5f);
  float t2 = (sal+svl)/(d3+0.5f);
  float t3 = (sav+sl)/(d4+0.5f);
  float t4 = (sal+sv)/(d5+0.5f);
  float t5 = (sa+svl)/(d6+0.5f);
  float mx = fmaxf(fmaxf(fmaxf(t0,t1),fmaxf(t2,t3)),fmaxf(t4,t5));
  float g0=__expf(t0-mx),g1=__expf(t1-mx),g2=__expf(t2-mx);
  float g3=__expf(t3-mx),g4=__expf(t4-mx),g5=__expf(t5-mx);
  float gs = g0+g1+g2+g3+g4+g5;
  if(lane == 0){
    float wt[6] = {g0/gs,g1/gs,g2/gs,g3/gs,g4/gs,g5/gs};
    float* twr = tw + (size_t)r*12;
    #pragma unroll
    for(int p = 0; p < 6; p++){ st[15+p] = wt[p]; twr[6+p] = wt[p]; }
  }
}

// ---------- K6 precompute: WpT (64 x 5120 bf16), BN folded ----------
__global__ __launch_bounds__(256) void k6_prew(
    const float* __restrict__ gamma, const float* __restrict__ l1W,
    u16* __restrict__ WpT)
{
  int kk = blockIdx.x * 256 + threadIdx.x;   // 0..5119 (grid.x = 20)
  int j  = blockIdx.y;                        // 0..63
  const float gsc = 1.0f / sqrtf(1.0f + 1e-5f);
  int korig; float sc;
  if(kk < 1024){ korig = kk; sc = 1.f; }
  else if(kk < 4096){ korig = 1024 + ((kk - 1024) & 1023); sc = 1.0f/3.0f; }
  else { korig = 2048 + (kk - 4096); sc = 1.f; }
  float v = (j < 50) ? l1W[(size_t)korig*50 + j] * gamma[korig] * gsc * sc : 0.f;
  WpT[(size_t)j*KF + kk] = f2bf(v);
}

// ---------- K6 precompute: bp[j] = l1b[j] + beta @ l1W ----------
__global__ __launch_bounds__(256) void k6_preb(
    const float* __restrict__ beta, const float* __restrict__ l1W,
    const float* __restrict__ l1b, float* __restrict__ bp)
{
  __shared__ float red[4][64];
  int j = threadIdx.x & 63, seg = threadIdx.x >> 6;
  float s = 0.f;
  if(j < 50){
    for(int k = seg*768; k < seg*768 + 768; k++)
      s = fmaf(beta[k], l1W[(size_t)k*50 + j], s);
  }
  red[seg][j] = s;
  __syncthreads();
  if(seg == 0){
    float t = red[0][j] + red[1][j] + red[2][j] + red[3][j];
    bp[j] = (j < 50) ? (l1b[j] + t) : 0.f;
  }
}

// ---------- K6 v3: (NB x 5120)@(5120 x 64) + MLP tail ----------
__global__ __launch_bounds__(256) void k6v3(
    const u16* __restrict__ Fcat, const u16* __restrict__ WpT,
    const float* __restrict__ bp,
    const float* __restrict__ l2W, const float* __restrict__ l2b,
    const float* __restrict__ l3W, const float* __restrict__ l3b,
    float* __restrict__ y2out)
{
  __shared__ __align__(16) char smem[29760];
  u16*  Asm = (u16*)smem;                          // [2][2048] = 8 KB (stage)
  float* W2s = (float*)(smem + 8192);              // [50][64]  = 12.8 KB
  float* W3s = (float*)(smem + 8192 + 12800);      // [50][8]   = 1.6 KB
  float* Ys  = (float*)smem;                       // [32][56]  aliases Asm (7 KB)
  float* Ys2 = (float*)(smem + 8192 + 12800 + 1600); // [32][56] = 7 KB

  int tid = threadIdx.x;
  int wv = tid >> 6, lane = tid & 63;
  int fr = lane & 15, kg = lane >> 4;
  int rb = blockIdx.x * 32;

  for(int t = tid; t < 3200; t += 256){
    int c = t & 63;
    W2s[t] = (c < 50) ? l2W[(t >> 6)*50 + c] : 0.f;
  }
  for(int t = tid; t < 400; t += 256) W3s[t] = l3W[t];

  int r8 = lane >> 3, pp = lane & 7;
  int sp = pp ^ r8;
  const u16* gsrc = Fcat + (size_t)(rb + wv*8 + r8)*KF + sp*8;
  const u16* bptr = WpT  + (size_t)(fr)*KF + (size_t)wv*16*KF + kg*8;

  f32x4 acc[2];
  acc[0] = (f32x4){0.f,0.f,0.f,0.f};
  acc[1] = (f32x4){0.f,0.f,0.f,0.f};

  gll16(gsrc, &Asm[wv*512]);
  __syncthreads();

  int buf = 0;
  for(int ci = 0; ci < 80; ci++){
    int k0 = ci*64;
    if(ci < 79)
      gll16(gsrc + k0 + 64, &Asm[(buf^1)*2048 + wv*512]);
    #pragma unroll
    for(int ks = 0; ks < 2; ks++){
      bf16x8 b = *(const bf16x8*)(bptr + k0 + ks*32);
      #pragma unroll
      for(int rf = 0; rf < 2; rf++){
        int row = rf*16 + fr;
        int slot = (ks*4 + kg) ^ (fr & 7);
        bf16x8 a = *(const bf16x8*)&Asm[buf*2048 + row*64 + slot*8];
        acc[rf] = __builtin_amdgcn_mfma_f32_16x16x32_bf16(a, b, acc[rf], 0, 0, 0);
      }
    }
    __syncthreads();
    buf ^= 1;
  }

  {
    int col = wv*16 + fr;
    float bpc = bp[col];
    #pragma unroll
    for(int rf = 0; rf < 2; rf++)
      #pragma unroll
      for(int q = 0; q < 4; q++){
        int row = rf*16 + kg*4 + q;
        if(col < 50) Ys[row*56 + col] = fast_tanh(acc[rf][q] + bpc);
      }
  }
  __syncthreads();

  {
    int r = tid >> 3, cg = (tid & 7) * 7;
    float a2[7] = {0,0,0,0,0,0,0};
    for(int k = 0; k < 50; k++){
      float yv = Ys[r*56 + k];
      #pragma unroll
      for(int c = 0; c < 7; c++) a2[c] = fmaf(yv, W2s[k*64 + cg + c], a2[c]);
    }
    #pragma unroll
    for(int c = 0; c < 7; c++){
      int cc = cg + c;
      if(cc < 50) Ys2[r*56 + cc] = fast_tanh(a2[c] + l2b[cc]);
    }
  }
  __syncthreads();

  {
    int r = tid >> 3, c = tid & 7;
    float z = l3b[c];
    for(int k = 0; k < 50; k++) z = fmaf(Ys2[r*56 + k], W3s[k*8 + c], z);
    float m = z;
    m = fmaxf(m, __shfl_xor(m, 1));
    m = fmaxf(m, __shfl_xor(m, 2));
    m = fmaxf(m, __shfl_xor(m, 4));
    float e = __expf(z - m);
    float s = e;
    s += __shfl_xor(s, 1); s += __shfl_xor(s, 2); s += __shfl_xor(s, 4);
    y2out[(size_t)(rb + r)*8 + c] = e / s;
  }
}

// ---------- launch ----------
extern "C" void kernel_launch(void* const* d_in, const int* in_sizes, int n_in,
                              void* d_out, int out_size, void* d_ws, size_t ws_size,
                              hipStream_t stream)
{
  (void)in_sizes; (void)n_in; (void)out_size; (void)ws_size;
  const float* x    = (const float*)d_in[0];
  const float* attW = (const float*)d_in[1];
  const float* attb = (const float*)d_in[2];
  const float* gfW1 = (const float*)d_in[3];
  const float* gfb1 = (const float*)d_in[4];
  const float* gfW2 = (const float*)d_in[5];
  const float* gfb2 = (const float*)d_in[6];
  const float* bng  = (const float*)d_in[7];
  const float* bnb  = (const float*)d_in[8];
  const float* l1W  = (const float*)d_in[9];
  const float* l1b  = (const float*)d_in[10];
  const float* l2W  = (const float*)d_in[11];
  const float* l2b  = (const float*)d_in[12];
  const float* l3W  = (const float*)d_in[13];
  const float* l3b  = (const float*)d_in[14];

  float* out = (float*)d_out;
  float* tw  = out + (size_t)NB*8;

  // workspace layout
  float* ws    = (float*)d_ws;
  float* stats = ws;                               // NB*24 f32
  float* UV1   = stats + (size_t)NB*24;            // 3*NB*128 f32
  float* UV2   = UV1 + (size_t)3*NB*128;           // 3*NB*128 f32
  float* bp    = UV2 + (size_t)3*NB*128;           // 64 f32
  u16* WpT     = (u16*)(bp + 64);                  // 64*KF bf16
  u16* Wb1     = WpT + (size_t)64*KF;              // 128*1024 bf16
  u16* W2T     = Wb1 + (size_t)128*1024;           // 1024*64 bf16
  u16* Fcat    = W2T + (size_t)1024*64;            // NB*KF bf16

  k1_stats<<<dim3(NB/4), dim3(256), 0, stream>>>(x, attW, attb, stats, Fcat, tw);
  kprew_b1<<<dim3(512), dim3(256), 0, stream>>>(gfW1, Wb1);
  kprew_w2t<<<dim3(256), dim3(256), 0, stream>>>(gfW2, W2T);
  k6_prew<<<dim3(20, 64), dim3(256), 0, stream>>>(bng, l1W, WpT);
  k6_preb<<<dim3(1), dim3(256), 0, stream>>>(bnb, l1W, l1b, bp);

  kg1v2<1><<<dim3(3*NB/64), dim3(256), 0, stream>>>(x, (const u16*)nullptr, Wb1, UV1);
  kL2v2<3,0><<<dim3(NB/16, 4), dim3(256), 0, stream>>>(UV1, UV1, W2T, gfb1, gfb2, stats, Fcat);
  k3s_stats2<<<dim3(NB/4), dim3(256), 0, stream>>>(Fcat, x, stats, tw);
  kg1v2<0><<<dim3(3*NB/64), dim3(256), 0, stream>>>((const float*)nullptr, Fcat, Wb1, UV2);
  kL2v2<6,1><<<dim3(NB/16, 4), dim3(256), 0, stream>>>(UV2, UV1, W2T, gfb1, gfb2, stats, Fcat);
  k6v3<<<dim3(NB/32), dim3(256), 0, stream>>>(Fcat, WpT, bp, l2W, l2b, l3W, l3b, out);
}